// Round 8
// baseline (316.287 us; speedup 1.0000x reference)
//
#include <hip/hip_runtime.h>

#define NNODES 65536
#define NEDGES 1048576
#define NGRAPH 64
#define NPERG  1024
#define KEEP   512
#define M2     (NGRAPH * KEEP)   // 32768
#define HD     128
#define NC     10

// canonical weight block offsets (floats)
#define OW1 0
#define OW2 16384
#define OWL 32768
#define OB1 34048
#define OB2 34176
#define OP  34304
#define OBL 34432
#define NCVT 34448

typedef __attribute__((ext_vector_type(8))) short bf16x8;
typedef __attribute__((ext_vector_type(4))) float f32x4;

__device__ __forceinline__ float bf2f(unsigned short u) {
    return __uint_as_float(((unsigned int)u) << 16);
}
__device__ __forceinline__ unsigned short f2bf(float f) {
    unsigned int u = __float_as_uint(f);
    unsigned int r = (u + 0x7FFFu + ((u >> 16) & 1u)) >> 16;
    return (unsigned short)r;
}

// ------- prep: detect dtype + cvt weights + pnorm + init + hist partials -----
__global__ __launch_bounds__(256) void prep_kernel(
    const void* __restrict__ W1, const void* __restrict__ b1, const void* __restrict__ p,
    const void* __restrict__ W2, const void* __restrict__ b2, const void* __restrict__ Wl,
    const void* __restrict__ bl, int* __restrict__ flag, float* __restrict__ cw,
    float* __restrict__ invnorm, int* __restrict__ new_id, int* __restrict__ ghist,
    int* __restrict__ gcur0, float* __restrict__ pooled,
    unsigned short* __restrict__ w1t, unsigned short* __restrict__ w2t,
    const int* __restrict__ src, int* __restrict__ phist,
    int* __restrict__ deg1, int* __restrict__ cur) {
    int bid = blockIdx.x, t = threadIdx.x;
    const unsigned short* w1u = (const unsigned short*)W1;
    int local = 0;
    for (int i = t; i < 512; i += 256) {
        unsigned short u = w1u[2 * i];
        int e = (u >> 7) & 0xFF;
        local += (e >= 100 && e <= 140) ? 1 : 0;
    }
    __shared__ int red[256];
    __shared__ int lh[NGRAPH];
    red[t] = local;
    __syncthreads();
    for (int off = 128; off; off >>= 1) {
        if (t < off) red[t] += red[t + off];
        __syncthreads();
    }
    int fl = (red[0] >= 384) ? 1 : 0;
    if (bid == 0 && t == 0) flag[0] = fl;

    if (bid < 135) {
        int gid = bid * 256 + t;
        if (gid < NCVT) {
            const void* srcp; int idx;
            if (gid < OB1) {
                if (gid < OW2)      { srcp = W1; idx = gid - OW1; }
                else if (gid < OWL) { srcp = W2; idx = gid - OW2; }
                else                { srcp = Wl; idx = gid - OWL; }
            } else {
                if (gid < OB2)      { srcp = b1; idx = gid - OB1; }
                else if (gid < OP)  { srcp = b2; idx = gid - OB2; }
                else if (gid < OBL) { srcp = p;  idx = gid - OP; }
                else                { srcp = bl; idx = gid - OBL; }
            }
            float v;
            if (gid >= OWL && gid < OB1 && idx >= 1280) v = 0.f;       // Wl pad
            else if (gid >= OBL && idx >= NC) v = 0.f;                  // bl pad
            else if (fl) v = bf2f(((const unsigned short*)srcp)[idx]);
            else v = ((const float*)srcp)[idx];
            cw[gid] = v;
            // bf16 transposed copies for the MFMA paths: w1t[n][k], w2t[n][k]
            if (gid < OW2) {
                int k = gid >> 7, n = gid & 127;
                w1t[n * 128 + k] = f2bf(v);
            } else if (gid < OWL) {
                int r = gid - OW2;
                int k = r >> 7, n = r & 127;
                w2t[n * 128 + k] = f2bf(v);
            }
        }
    } else if (bid == 135) {
        __shared__ float s2a[128];
        float pv = 0.f;
        if (t < 128) pv = fl ? bf2f(((const unsigned short*)p)[t]) : ((const float*)p)[t];
        if (t < 128) s2a[t] = pv * pv;
        __syncthreads();
        for (int off = 64; off; off >>= 1) {
            if (t < off) s2a[t] += s2a[t + off];
            __syncthreads();
        }
        if (t == 0) invnorm[0] = 1.0f / sqrtf(s2a[0]);
    } else if (bid < 392) {
        int i = (bid - 136) * 256 + t;
        new_id[i] = -1;
        deg1[i] = 0;
        cur[i] = 0;
        if (i < NGRAPH) { ghist[i] = 0; gcur0[i] = 0; }
        if (i < NGRAPH * HD) pooled[i] = 0.f;
    } else {
        // ---- edge histogram partials ----
        if (t < NGRAPH) lh[t] = 0;
        __syncthreads();
        int e0 = (bid - 392) * 4096;
        for (int k = 0; k < 16; k++) atomicAdd(&lh[src[e0 + k * 256 + t] >> 10], 1);
        __syncthreads();
        if (t < NGRAPH) phist[(bid - 392) * 64 + t] = lh[t];
    }
}

// ------ edge binning by graph (reduces hist partials) + global deg1 count ----
__global__ __launch_bounds__(256) void binpass_kernel(const int* __restrict__ src,
                                                      const int* __restrict__ dst,
                                                      const int* __restrict__ phist,
                                                      int* __restrict__ ghist,
                                                      int* __restrict__ gcur0,
                                                      unsigned int* __restrict__ elist,
                                                      int* __restrict__ deg1) {
    __shared__ int gh[NGRAPH];
    __shared__ int gbS[NGRAPH];
    __shared__ int lh[NGRAPH];
    __shared__ int lbase[NGRAPH];
    __shared__ int qsum[4][NGRAPH];
    int tid = threadIdx.x;
    {
        int g = tid & 63, q = tid >> 6;
        int s = 0;
        for (int b = q * 64; b < q * 64 + 64; b++) s += phist[b * 64 + g];
        qsum[q][g] = s;
    }
    __syncthreads();
    if (tid < NGRAPH) {
        gh[tid] = qsum[0][tid] + qsum[1][tid] + qsum[2][tid] + qsum[3][tid];
        lh[tid] = 0;
        if (blockIdx.x == 0) ghist[tid] = gh[tid];  // publish for downstream
    }
    __syncthreads();
    if (tid == 0) {
        int s = 0;
        for (int i = 0; i < NGRAPH; i++) { gbS[i] = s; s += gh[i]; }
    }
    __syncthreads();
    int e0 = blockIdx.x * 4096;  // 256 blocks
    int gs[16]; unsigned int pk[16];
    for (int k = 0; k < 16; k++) {
        int e = e0 + k * 256 + tid;
        int s = src[e], d = dst[e];
        gs[k] = s >> 10;
        pk[k] = (unsigned)(s & 1023) | ((unsigned)(d & 1023) << 10);
        atomicAdd(&lh[gs[k]], 1);
        atomicAdd(&deg1[gs[k] * NPERG + (d & 1023)], 1);   // global dst-degree
    }
    __syncthreads();
    if (tid < NGRAPH) { lbase[tid] = gbS[tid] + atomicAdd(&gcur0[tid], lh[tid]); lh[tid] = 0; }
    __syncthreads();
    for (int k = 0; k < 16; k++) {
        int g = gs[k];
        int pos = lbase[g] + atomicAdd(&lh[g], 1);
        elist[pos] = pk[k];
    }
}

// ---------------- FUSED: per-graph node_base scan (blocks 0..63) -------------
// ---------------- + GEMM1 xw1 = A @ W1 via MFMA (blocks 64..319) ------------
// Scan is tiny now (counting moved to binpass, scatter to its own kernel);
// no big LDS -> GEMM blocks schedule freely.
__global__ __launch_bounds__(1024) void g1scan_kernel(
    const int* __restrict__ ghist, const int* __restrict__ deg1,
    int* __restrict__ node_base, float* __restrict__ dinv_out,
    const void* __restrict__ Araw, const unsigned short* __restrict__ Wtb,
    unsigned int* __restrict__ Cb, const int* __restrict__ flag) {
    __shared__ int wsum[16];
    __shared__ int gh[NGRAPH];
    __shared__ int baseS;
    int bid = blockIdx.x, t = threadIdx.x;
    if (bid < NGRAPH) {
        int g = bid;
        if (t < NGRAPH) gh[t] = ghist[t];
        __syncthreads();
        if (t == 0) {
            int s = 0;
            for (int i = 0; i < g; i++) s += gh[i];
            baseS = s;
        }
        __syncthreads();
        int v = deg1[g * NPERG + t];
        int lane = t & 63;
        int x = v;
        for (int off = 1; off < 64; off <<= 1) {
            int y = __shfl_up(x, off);
            if (lane >= off) x += y;
        }
        if (lane == 63) wsum[t >> 6] = x;
        __syncthreads();
        if (t < 16) {
            int wv = wsum[t];
            int wx = wv;
            for (int off = 1; off < 16; off <<= 1) {
                int y = __shfl_up(wx, off);
                if (t >= off) wx += y;
            }
            wsum[t] = wx - wv;  // exclusive wave base
        }
        __syncthreads();
        int excl = x - v + wsum[t >> 6];
        dinv_out[g * NPERG + t] = rsqrtf((float)v + 1.0f);
        node_base[g * NPERG + t] = baseS + excl;
        return;
    }
    // ---- GEMM1 path: 16 waves/block, 16 rows/wave = 256 rows/block ----
    int row0 = (bid - NGRAPH) * 256;
    int wave = t >> 6, lane = t & 63;
    int r0 = row0 + wave * 16;
    int row = r0 + (lane & 15);
    int ko = (lane >> 4) * 8;                    // k offset within 32-chunk
    f32x4 acc[8];
#pragma unroll
    for (int c = 0; c < 8; c++) acc[c] = (f32x4){0.f, 0.f, 0.f, 0.f};
    bf16x8 afr[4];
    if (flag[0]) {
        const unsigned short* arow = (const unsigned short*)Araw + (size_t)row * HD + ko;
#pragma unroll
        for (int kk = 0; kk < 4; kk++) afr[kk] = *(const bf16x8*)(arow + kk * 32);
    } else {
        const float* arow = (const float*)Araw + (size_t)row * HD + ko;
#pragma unroll
        for (int kk = 0; kk < 4; kk++) {
            float4 f0 = *(const float4*)(arow + kk * 32);
            float4 f1 = *(const float4*)(arow + kk * 32 + 4);
            bf16x8 a;
            a[0] = (short)f2bf(f0.x); a[1] = (short)f2bf(f0.y);
            a[2] = (short)f2bf(f0.z); a[3] = (short)f2bf(f0.w);
            a[4] = (short)f2bf(f1.x); a[5] = (short)f2bf(f1.y);
            a[6] = (short)f2bf(f1.z); a[7] = (short)f2bf(f1.w);
            afr[kk] = a;
        }
    }
    const unsigned short* brow = Wtb + (lane & 15) * HD + ko;
#pragma unroll
    for (int kk = 0; kk < 4; kk++) {
#pragma unroll
        for (int c = 0; c < 8; c++) {
            bf16x8 b = *(const bf16x8*)(brow + c * 16 * HD + kk * 32);
            acc[c] = __builtin_amdgcn_mfma_f32_16x16x32_bf16(afr[kk], b, acc[c], 0, 0, 0);
        }
    }
    int orow0 = r0 + (lane >> 4) * 4;
    bool even = !(lane & 1);
#pragma unroll
    for (int c = 0; c < 8; c++) {
#pragma unroll
        for (int j = 0; j < 4; j++) {
            float v = acc[c][j];
            float pt = __shfl_xor(v, 1);
            if (even) {
                unsigned int u = (unsigned int)f2bf(v) | ((unsigned int)f2bf(pt) << 16);
                Cb[(size_t)(orow0 + j) * 64 + ((c * 16 + (lane & 15)) >> 1)] = u;
            }
        }
    }
}

// ---------------- wide CSR scatter: 4 blocks/graph, global atomic cursors ----
// Per-node edge order becomes nondeterministic (sum-reorder only; the edge
// multiset per node is identical).
__global__ __launch_bounds__(256) void scatter_kernel(
    const unsigned int* __restrict__ elist, const int* __restrict__ ghist,
    const int* __restrict__ node_base, int* __restrict__ cur,
    unsigned short* __restrict__ csr16) {
    __shared__ int gh[NGRAPH];
    __shared__ int baseS;
    int b = blockIdx.x;
    int g = b >> 2, q = b & 3;
    int t = threadIdx.x;
    if (t < NGRAPH) gh[t] = ghist[t];
    __syncthreads();
    if (t == 0) {
        int s = 0;
        for (int i = 0; i < g; i++) s += gh[i];
        baseS = s;
    }
    __syncthreads();
    int base = baseS, n = gh[g];
    int chunk = (n + 3) >> 2;
    int j0 = q * chunk;
    int j1 = j0 + chunk; if (j1 > n) j1 = n;
    int gb = g * NPERG;
    for (int j = j0 + t; j < j1; j += 256) {
        unsigned int pk = elist[base + j];
        int d = (pk >> 10) & 1023;
        int pos = node_base[gb + d] + atomicAdd(&cur[gb + d], 1);
        csr16[pos] = (unsigned short)(pk & 1023);
    }
}

// ---------------- conv1 aggregate (pull, 8-deep batched, bf16 rows) ----------
__global__ __launch_bounds__(256) void s1_pull(const unsigned short* __restrict__ csr16,
                                               const int* __restrict__ node_base,
                                               const int* __restrict__ deg,
                                               const float* __restrict__ dinv,
                                               const unsigned int* __restrict__ xwb,
                                               const float* __restrict__ b1,
                                               const float* __restrict__ pvec,
                                               const float* __restrict__ invnorm,
                                               unsigned int* __restrict__ hb,
                                               float* __restrict__ score) {
    int b = blockIdx.x;                 // 16384 blocks
    int xcd = b & 7, j = b >> 3;        // XCD-swizzle: graph pinned to one XCD
    int g = (j >> 8) * 8 + xcd;
    int n = g * NPERG + (j & 255) * 4 + (threadIdx.x >> 6);
    int lane = threadIdx.x & 63;
    int gb = g * NPERG;
    int base = node_base[n], cnt = deg[n];
    int e = 0; float ds = 0.f;
    if (lane < cnt) {
        e = csr16[base + lane];
        ds = dinv[gb + e];
    }
    float a0 = 0.f, a1 = 0.f;
    int klim = cnt < 64 ? cnt : 64;
    int k = 0;
    for (; k + 7 < klim; k += 8) {
        int s0 = __shfl(e, k),     s1 = __shfl(e, k + 1);
        int s2 = __shfl(e, k + 2), s3 = __shfl(e, k + 3);
        int s4 = __shfl(e, k + 4), s5 = __shfl(e, k + 5);
        int s6 = __shfl(e, k + 6), s7 = __shfl(e, k + 7);
        float d0 = __shfl(ds, k),     d1 = __shfl(ds, k + 1);
        float d2 = __shfl(ds, k + 2), d3 = __shfl(ds, k + 3);
        float d4 = __shfl(ds, k + 4), d5 = __shfl(ds, k + 5);
        float d6 = __shfl(ds, k + 6), d7 = __shfl(ds, k + 7);
        unsigned int u0 = xwb[(size_t)(gb + s0) * 64 + lane];
        unsigned int u1 = xwb[(size_t)(gb + s1) * 64 + lane];
        unsigned int u2 = xwb[(size_t)(gb + s2) * 64 + lane];
        unsigned int u3 = xwb[(size_t)(gb + s3) * 64 + lane];
        unsigned int u4 = xwb[(size_t)(gb + s4) * 64 + lane];
        unsigned int u5 = xwb[(size_t)(gb + s5) * 64 + lane];
        unsigned int u6 = xwb[(size_t)(gb + s6) * 64 + lane];
        unsigned int u7 = xwb[(size_t)(gb + s7) * 64 + lane];
        a0 += d0 * __uint_as_float(u0 << 16); a1 += d0 * __uint_as_float(u0 & 0xFFFF0000u);
        a0 += d1 * __uint_as_float(u1 << 16); a1 += d1 * __uint_as_float(u1 & 0xFFFF0000u);
        a0 += d2 * __uint_as_float(u2 << 16); a1 += d2 * __uint_as_float(u2 & 0xFFFF0000u);
        a0 += d3 * __uint_as_float(u3 << 16); a1 += d3 * __uint_as_float(u3 & 0xFFFF0000u);
        a0 += d4 * __uint_as_float(u4 << 16); a1 += d4 * __uint_as_float(u4 & 0xFFFF0000u);
        a0 += d5 * __uint_as_float(u5 << 16); a1 += d5 * __uint_as_float(u5 & 0xFFFF0000u);
        a0 += d6 * __uint_as_float(u6 << 16); a1 += d6 * __uint_as_float(u6 & 0xFFFF0000u);
        a0 += d7 * __uint_as_float(u7 << 16); a1 += d7 * __uint_as_float(u7 & 0xFFFF0000u);
    }
    for (; k + 3 < klim; k += 4) {
        int s0 = __shfl(e, k), s1 = __shfl(e, k + 1);
        int s2 = __shfl(e, k + 2), s3 = __shfl(e, k + 3);
        float d0 = __shfl(ds, k), d1 = __shfl(ds, k + 1);
        float d2 = __shfl(ds, k + 2), d3 = __shfl(ds, k + 3);
        unsigned int u0 = xwb[(size_t)(gb + s0) * 64 + lane];
        unsigned int u1 = xwb[(size_t)(gb + s1) * 64 + lane];
        unsigned int u2 = xwb[(size_t)(gb + s2) * 64 + lane];
        unsigned int u3 = xwb[(size_t)(gb + s3) * 64 + lane];
        a0 += d0 * __uint_as_float(u0 << 16); a1 += d0 * __uint_as_float(u0 & 0xFFFF0000u);
        a0 += d1 * __uint_as_float(u1 << 16); a1 += d1 * __uint_as_float(u1 & 0xFFFF0000u);
        a0 += d2 * __uint_as_float(u2 << 16); a1 += d2 * __uint_as_float(u2 & 0xFFFF0000u);
        a0 += d3 * __uint_as_float(u3 << 16); a1 += d3 * __uint_as_float(u3 & 0xFFFF0000u);
    }
    for (; k < klim; k++) {
        int sk = __shfl(e, k);
        float dk = __shfl(ds, k);
        unsigned int u = xwb[(size_t)(gb + sk) * 64 + lane];
        a0 += dk * __uint_as_float(u << 16); a1 += dk * __uint_as_float(u & 0xFFFF0000u);
    }
    for (; k < cnt; k++) {  // deg>64 cold path (P ~ 0, correctness only)
        int sk = csr16[base + k];
        float dk = dinv[gb + sk];
        unsigned int u = xwb[(size_t)(gb + sk) * 64 + lane];
        a0 += dk * __uint_as_float(u << 16); a1 += dk * __uint_as_float(u & 0xFFFF0000u);
    }
    float dn = dinv[n];
    float self = dn * dn;
    unsigned int us = xwb[(size_t)n * 64 + lane];
    float2 bb = ((const float2*)b1)[lane];
    float h0 = fmaxf(dn * a0 + self * __uint_as_float(us << 16) + bb.x, 0.f);
    float h1 = fmaxf(dn * a1 + self * __uint_as_float(us & 0xFFFF0000u) + bb.y, 0.f);
    hb[(size_t)n * 64 + lane] = (unsigned int)f2bf(h0) | ((unsigned int)f2bf(h1) << 16);
    float2 pp = ((const float2*)pvec)[lane];
    float sv = h0 * pp.x + h1 * pp.y;
    for (int off = 32; off; off >>= 1) sv += __shfl_down(sv, off);
    if (lane == 0) score[n] = tanhf(sv * invnorm[0]);
}

// ---------------- top-512 bitonic: register-resident, shuffle for j<64 -------
__global__ __launch_bounds__(1024) void topk_kernel(const float* __restrict__ score,
                                                    float* __restrict__ vals,
                                                    int* __restrict__ perm,
                                                    int* __restrict__ new_id) {
    __shared__ float sv[1024];
    __shared__ int si[1024];
    int g = blockIdx.x, t = threadIdx.x;
    float v = score[g * NPERG + t];
    int idx = t;
    for (int k = 2; k <= 1024; k <<= 1) {
        for (int j = k >> 1; j > 0; j >>= 1) {
            bool desc = ((t & k) == 0);
            bool up = (t & j) != 0;
            float vb; int ib;
            if (j >= 64) {
                sv[t] = v; si[t] = idx;
                __syncthreads();
                vb = sv[t ^ j]; ib = si[t ^ j];
                bool cmp = (v > vb) || (v == vb && idx < ib);  // lax.top_k tie rule
                bool keep = up ? (cmp != desc) : (cmp == desc);
                if (!keep) { v = vb; idx = ib; }
                __syncthreads();
            } else {
                vb = __shfl_xor(v, j);
                ib = __shfl_xor(idx, j);
                bool cmp = (v > vb) || (v == vb && idx < ib);
                bool keep = up ? (cmp != desc) : (cmp == desc);
                if (!keep) { v = vb; idx = ib; }
            }
        }
    }
    if (t < KEEP) {
        int node = g * NPERG + idx;
        int slot = g * KEEP + t;
        vals[slot] = v;
        perm[slot] = node;
        new_id[node] = slot;
    }
}

// ---------------- FUSED: deg2/dinv2 edge-pass (blocks 0..63) -----------------
// ---------------- + GEMM2 (vals*h[perm]) @ W2 MFMA, bf16-packed out ----------
__global__ __launch_bounds__(512) void g2deg_kernel(
    const unsigned int* __restrict__ elist, const int* __restrict__ ghist,
    const int* __restrict__ new_id, float* __restrict__ dinv2,
    const unsigned int* __restrict__ hb, const int* __restrict__ perm,
    const float* __restrict__ vals, const unsigned short* __restrict__ Wtb,
    unsigned int* __restrict__ Cb) {
    __shared__ int d2[KEEP];
    __shared__ int gh[NGRAPH];
    __shared__ int baseS, nS;
    int bid = blockIdx.x, t = threadIdx.x;
    if (bid < NGRAPH) {
        int g = bid;
        if (t < KEEP) d2[t] = 0;
        if (t < NGRAPH) gh[t] = ghist[t];
        __syncthreads();
        if (t == 0) {
            int s = 0;
            for (int i = 0; i < g; i++) s += gh[i];
            baseS = s; nS = gh[g];
        }
        __syncthreads();
        int base = baseS, n = nS;
        int gb = g * NPERG;
        int kb = g * KEEP;
        for (int j = t; j < n; j += 512) {
            unsigned int pk = elist[base + j];
            int s = pk & 1023, d = (pk >> 10) & 1023;
            int ns = new_id[gb + s], nd = new_id[gb + d];
            if (ns >= 0 && nd >= 0) atomicAdd(&d2[nd - kb], 1);
        }
        __syncthreads();
        if (t < KEEP) dinv2[kb + t] = rsqrtf((float)d2[t] + 1.0f);
        return;
    }
    // ---- GEMM2 path: 8 waves/block, 16 rows/wave = 128 rows/block ----
    int row0 = (bid - NGRAPH) * 128;
    int wave = t >> 6, lane = t & 63;
    int r0 = row0 + wave * 16;
    int m = r0 + (lane & 15);
    int ko = (lane >> 4) * 8;
    float sc = vals[m];
    const unsigned int* arow = hb + (size_t)perm[m] * 64 + (ko >> 1);
    bf16x8 afr[4];
#pragma unroll
    for (int kk = 0; kk < 4; kk++) {
        uint4 q = *(const uint4*)(arow + kk * 16);
        bf16x8 a;
        a[0] = (short)f2bf(bf2f((unsigned short)q.x) * sc);
        a[1] = (short)f2bf(bf2f((unsigned short)(q.x >> 16)) * sc);
        a[2] = (short)f2bf(bf2f((unsigned short)q.y) * sc);
        a[3] = (short)f2bf(bf2f((unsigned short)(q.y >> 16)) * sc);
        a[4] = (short)f2bf(bf2f((unsigned short)q.z) * sc);
        a[5] = (short)f2bf(bf2f((unsigned short)(q.z >> 16)) * sc);
        a[6] = (short)f2bf(bf2f((unsigned short)q.w) * sc);
        a[7] = (short)f2bf(bf2f((unsigned short)(q.w >> 16)) * sc);
        afr[kk] = a;
    }
    f32x4 acc[8];
#pragma unroll
    for (int c = 0; c < 8; c++) acc[c] = (f32x4){0.f, 0.f, 0.f, 0.f};
    const unsigned short* brow = Wtb + (lane & 15) * HD + ko;
#pragma unroll
    for (int kk = 0; kk < 4; kk++) {
#pragma unroll
        for (int c = 0; c < 8; c++) {
            bf16x8 b = *(const bf16x8*)(brow + c * 16 * HD + kk * 32);
            acc[c] = __builtin_amdgcn_mfma_f32_16x16x32_bf16(afr[kk], b, acc[c], 0, 0, 0);
        }
    }
    int orow0 = r0 + (lane >> 4) * 4;
    bool even = !(lane & 1);
#pragma unroll
    for (int c = 0; c < 8; c++) {
#pragma unroll
        for (int j = 0; j < 4; j++) {
            float v = acc[c][j];
            float pt = __shfl_xor(v, 1);
            if (even) {
                unsigned int u = (unsigned int)f2bf(v) | ((unsigned int)f2bf(pt) << 16);
                Cb[(size_t)(orow0 + j) * 64 + ((c * 16 + (lane & 15)) >> 1)] = u;
            }
        }
    }
}

// ---------------- conv2 aggregate: ballot-compact + bf16 rows + pool ---------
__global__ __launch_bounds__(256) void s2_pull(const unsigned short* __restrict__ csr16,
                                               const int* __restrict__ node_base,
                                               const int* __restrict__ deg,
                                               const int* __restrict__ perm,
                                               const int* __restrict__ new_id,
                                               const float* __restrict__ dinv2,
                                               const unsigned int* __restrict__ xwb2,
                                               const float* __restrict__ b2,
                                               float* __restrict__ pooled) {
    __shared__ float pr[HD];
    __shared__ int cnk[4][64];
    __shared__ float cds[4][64];
    int tid = threadIdx.x;
    if (tid < HD) pr[tid] = 0.f;
    __syncthreads();
    int b = blockIdx.x;              // 8192 blocks
    int xcd = b & 7, j = b >> 3;
    int g = (j >> 7) * 8 + xcd;
    int wv = tid >> 6;
    int m = g * KEEP + (j & 127) * 4 + wv;
    int lane = tid & 63;
    int node = perm[m];
    int gb = node & ~(NPERG - 1);
    int base = node_base[node], cnt = deg[node];
    int nk = 0; float ds = 0.f;
    if (lane < cnt) {
        int ns = new_id[gb + csr16[base + lane]];
        if (ns >= 0) { nk = ns; ds = dinv2[ns]; }
    }
    // ballot-compact survivors into per-wave LDS (ascending lane order)
    unsigned long long msk = __ballot(ds != 0.f);
    int pos = __popcll(msk & ((1ull << lane) - 1ull));
    if (ds != 0.f) { cnk[wv][pos] = nk; cds[wv][pos] = ds; }
    int na = __popcll(msk);
    float a0 = 0.f, a1 = 0.f;
    int k = 0;
    for (; k + 7 < na; k += 8) {
        int s0 = cnk[wv][k],     s1 = cnk[wv][k + 1];
        int s2 = cnk[wv][k + 2], s3 = cnk[wv][k + 3];
        int s4 = cnk[wv][k + 4], s5 = cnk[wv][k + 5];
        int s6 = cnk[wv][k + 6], s7 = cnk[wv][k + 7];
        float d0 = cds[wv][k],     d1 = cds[wv][k + 1];
        float d2 = cds[wv][k + 2], d3 = cds[wv][k + 3];
        float d4 = cds[wv][k + 4], d5 = cds[wv][k + 5];
        float d6 = cds[wv][k + 6], d7 = cds[wv][k + 7];
        unsigned int u0 = xwb2[(size_t)s0 * 64 + lane];
        unsigned int u1 = xwb2[(size_t)s1 * 64 + lane];
        unsigned int u2 = xwb2[(size_t)s2 * 64 + lane];
        unsigned int u3 = xwb2[(size_t)s3 * 64 + lane];
        unsigned int u4 = xwb2[(size_t)s4 * 64 + lane];
        unsigned int u5 = xwb2[(size_t)s5 * 64 + lane];
        unsigned int u6 = xwb2[(size_t)s6 * 64 + lane];
        unsigned int u7 = xwb2[(size_t)s7 * 64 + lane];
        a0 += d0 * __uint_as_float(u0 << 16); a1 += d0 * __uint_as_float(u0 & 0xFFFF0000u);
        a0 += d1 * __uint_as_float(u1 << 16); a1 += d1 * __uint_as_float(u1 & 0xFFFF0000u);
        a0 += d2 * __uint_as_float(u2 << 16); a1 += d2 * __uint_as_float(u2 & 0xFFFF0000u);
        a0 += d3 * __uint_as_float(u3 << 16); a1 += d3 * __uint_as_float(u3 & 0xFFFF0000u);
        a0 += d4 * __uint_as_float(u4 << 16); a1 += d4 * __uint_as_float(u4 & 0xFFFF0000u);
        a0 += d5 * __uint_as_float(u5 << 16); a1 += d5 * __uint_as_float(u5 & 0xFFFF0000u);
        a0 += d6 * __uint_as_float(u6 << 16); a1 += d6 * __uint_as_float(u6 & 0xFFFF0000u);
        a0 += d7 * __uint_as_float(u7 << 16); a1 += d7 * __uint_as_float(u7 & 0xFFFF0000u);
    }
    for (; k + 3 < na; k += 4) {
        int s0 = cnk[wv][k], s1 = cnk[wv][k + 1];
        int s2 = cnk[wv][k + 2], s3 = cnk[wv][k + 3];
        float d0 = cds[wv][k], d1 = cds[wv][k + 1];
        float d2 = cds[wv][k + 2], d3 = cds[wv][k + 3];
        unsigned int u0 = xwb2[(size_t)s0 * 64 + lane];
        unsigned int u1 = xwb2[(size_t)s1 * 64 + lane];
        unsigned int u2 = xwb2[(size_t)s2 * 64 + lane];
        unsigned int u3 = xwb2[(size_t)s3 * 64 + lane];
        a0 += d0 * __uint_as_float(u0 << 16); a1 += d0 * __uint_as_float(u0 & 0xFFFF0000u);
        a0 += d1 * __uint_as_float(u1 << 16); a1 += d1 * __uint_as_float(u1 & 0xFFFF0000u);
        a0 += d2 * __uint_as_float(u2 << 16); a1 += d2 * __uint_as_float(u2 & 0xFFFF0000u);
        a0 += d3 * __uint_as_float(u3 << 16); a1 += d3 * __uint_as_float(u3 & 0xFFFF0000u);
    }
    for (; k < na; k++) {
        int sk = cnk[wv][k];
        float dk = cds[wv][k];
        unsigned int u = xwb2[(size_t)sk * 64 + lane];
        a0 += dk * __uint_as_float(u << 16); a1 += dk * __uint_as_float(u & 0xFFFF0000u);
    }
    for (int kk = 64; kk < cnt; kk++) {    // deg>64 cold path
        int ns = new_id[gb + csr16[base + kk]];
        if (ns >= 0) {
            float dk = dinv2[ns];
            unsigned int u = xwb2[(size_t)ns * 64 + lane];
            a0 += dk * __uint_as_float(u << 16); a1 += dk * __uint_as_float(u & 0xFFFF0000u);
        }
    }
    float dn = dinv2[m];
    float self = dn * dn;
    unsigned int us = xwb2[(size_t)m * 64 + lane];
    float2 bb = ((const float2*)b2)[lane];
    float o0 = fmaxf(dn * a0 + self * __uint_as_float(us << 16) + bb.x, 0.f);
    float o1 = fmaxf(dn * a1 + self * __uint_as_float(us & 0xFFFF0000u) + bb.y, 0.f);
    atomicAdd(&pr[lane * 2], o0);
    atomicAdd(&pr[lane * 2 + 1], o1);
    __syncthreads();
    if (tid < HD) atomicAdd(&pooled[g * HD + tid], pr[tid]);
}

// ---------------- final linear: out = (pooled/512) @ Wl + bl -----------------
__global__ __launch_bounds__(128) void outk_kernel(const float* __restrict__ pooled,
                                                   const float* __restrict__ Wl,
                                                   const float* __restrict__ bl,
                                                   void* __restrict__ outv,
                                                   const int* __restrict__ flag) {
    int g = blockIdx.x, t = threadIdx.x;  // 128
    __shared__ float sp[HD];
    sp[t] = pooled[g * HD + t] * (1.0f / KEEP);
    __syncthreads();
    if (t < NC) {
        float acc = bl[t];
        for (int hh = 0; hh < HD; hh++) acc += sp[hh] * Wl[hh * NC + t];
        if (flag[0]) ((unsigned short*)outv)[g * NC + t] = f2bf(acc);
        else         ((float*)outv)[g * NC + t] = acc;
    }
}

extern "C" void kernel_launch(void* const* d_in, const int* in_sizes, int n_in,
                              void* d_out, int out_size, void* d_ws, size_t ws_size,
                              hipStream_t stream) {
    const int* ei   = (const int*)d_in[1];
    const int* srcv = ei;
    const int* dstv = ei + NEDGES;

    char* w = (char*)d_ws;
    const size_t MB = 1u << 20;
    const size_t KB = 1024;
    float* dinv1     = (float*)(w + 0);                 // 256 KB
    float* score     = (float*)(w + 256 * KB);          // 256 KB
    float* vals      = (float*)(w + 512 * KB);          // 128 KB
    int*   perm      = (int*)(w + 640 * KB);            // 128 KB
    int*   new_id    = (int*)(w + 768 * KB);            // 256 KB
    int*   deg1      = (int*)(w + 1024 * KB);           // 256 KB
    int*   node_base = (int*)(w + 1280 * KB);           // 256 KB
    float* dinv2     = (float*)(w + 1536 * KB);         // 128 KB
    float* invnorm   = (float*)(w + 1664 * KB);
    int*   flag      = (int*)(w + 1664 * KB + 64);
    int*   ghist     = (int*)(w + 1664 * KB + 1024);
    int*   gcur0     = (int*)(w + 1664 * KB + 2048);
    float* cw        = (float*)(w + 1700 * KB);         // 135 KB canonical weights
    float* pooled    = (float*)(w + 1840 * KB);         // 32 KB
    unsigned short* w1t = (unsigned short*)(w + 1880 * KB);  // 32 KB bf16 W1^T
    unsigned short* w2t = (unsigned short*)(w + 1912 * KB);  // 32 KB bf16 W2^T
    int* phist       = (int*)(w + 1944 * KB);           // 64 KB hist partials
    unsigned int* xw1b = (unsigned int*)(w + 2 * MB);   // [2,18) MB  bf16-packed xw1
    unsigned int* xw2b = (unsigned int*)(w + 18 * MB);  // [18,26) MB bf16-packed xw2
    unsigned int* hb = (unsigned int*)(w + 34 * MB);    // [34,50) MB bf16-packed h
    int* cur         = (int*)(w + 50 * MB);             // 256 KB scatter cursors
    unsigned int* elist    = (unsigned int*)(w + 66 * MB);   // [66,70) MB
    unsigned short* csr16  = (unsigned short*)(w + 70 * MB); // [70,72) MB

    float* W1f = cw + OW1; float* W2f = cw + OW2; float* Wlf = cw + OWL;
    float* b1f = cw + OB1; float* b2f = cw + OB2; float* pf  = cw + OP;
    float* blf = cw + OBL;
    (void)W1f; (void)W2f;

    prep_kernel<<<648, 256, 0, stream>>>(d_in[3], d_in[4], d_in[5], d_in[6], d_in[7],
                                         d_in[8], d_in[9], flag, cw, invnorm, new_id,
                                         ghist, gcur0, pooled, w1t, w2t, srcv, phist,
                                         deg1, cur);
    binpass_kernel<<<256, 256, 0, stream>>>(srcv, dstv, phist, ghist, gcur0, elist, deg1);
    g1scan_kernel<<<NGRAPH + NNODES / 256, 1024, 0, stream>>>(
        ghist, deg1, node_base, dinv1, d_in[0], w1t, xw1b, flag);
    scatter_kernel<<<NGRAPH * 4, 256, 0, stream>>>(elist, ghist, node_base, cur, csr16);
    s1_pull<<<NNODES / 4, 256, 0, stream>>>(csr16, node_base, deg1, dinv1, xw1b, b1f, pf,
                                            invnorm, hb, score);
    topk_kernel<<<NGRAPH, 1024, 0, stream>>>(score, vals, perm, new_id);
    g2deg_kernel<<<NGRAPH + M2 / 128, 512, 0, stream>>>(
        elist, ghist, new_id, dinv2, hb, perm, vals, w2t, xw2b);
    s2_pull<<<M2 / 4, 256, 0, stream>>>(csr16, node_base, deg1, perm, new_id, dinv2,
                                        xw2b, b2f, pooled);
    outk_kernel<<<NGRAPH, 128, 0, stream>>>(pooled, Wlf, blf, d_out, flag);

    (void)in_sizes; (void)n_in; (void)out_size; (void)ws_size;
}

// Round 9
// 257.132 us; speedup vs baseline: 1.2301x; 1.2301x over previous
//
#include <hip/hip_runtime.h>

#define NNODES 65536
#define NEDGES 1048576
#define NGRAPH 64
#define NPERG  1024
#define KEEP   512
#define M2     (NGRAPH * KEEP)   // 32768
#define HD     128
#define NC     10
#define EMAX   20480             // per-graph edge capacity (avg 16384, sigma~127)

// canonical weight block offsets (floats)
#define OW1 0
#define OW2 16384
#define OWL 32768
#define OB1 34048
#define OB2 34176
#define OP  34304
#define OBL 34432
#define NCVT 34448

typedef __attribute__((ext_vector_type(8))) short bf16x8;
typedef __attribute__((ext_vector_type(4))) float f32x4;

__device__ __forceinline__ float bf2f(unsigned short u) {
    return __uint_as_float(((unsigned int)u) << 16);
}
__device__ __forceinline__ unsigned short f2bf(float f) {
    unsigned int u = __float_as_uint(f);
    unsigned int r = (u + 0x7FFFu + ((u >> 16) & 1u)) >> 16;
    return (unsigned short)r;
}

// ------- prep: detect dtype + cvt weights + pnorm + init + hist partials -----
__global__ __launch_bounds__(256) void prep_kernel(
    const void* __restrict__ W1, const void* __restrict__ b1, const void* __restrict__ p,
    const void* __restrict__ W2, const void* __restrict__ b2, const void* __restrict__ Wl,
    const void* __restrict__ bl, int* __restrict__ flag, float* __restrict__ cw,
    float* __restrict__ invnorm, int* __restrict__ new_id, int* __restrict__ ghist,
    int* __restrict__ gcur0, float* __restrict__ pooled,
    unsigned short* __restrict__ w1t, unsigned short* __restrict__ w2t,
    const int* __restrict__ src, int* __restrict__ phist) {
    int bid = blockIdx.x, t = threadIdx.x;
    const unsigned short* w1u = (const unsigned short*)W1;
    int local = 0;
    for (int i = t; i < 512; i += 256) {
        unsigned short u = w1u[2 * i];
        int e = (u >> 7) & 0xFF;
        local += (e >= 100 && e <= 140) ? 1 : 0;
    }
    __shared__ int red[256];
    __shared__ int lh[NGRAPH];
    red[t] = local;
    __syncthreads();
    for (int off = 128; off; off >>= 1) {
        if (t < off) red[t] += red[t + off];
        __syncthreads();
    }
    int fl = (red[0] >= 384) ? 1 : 0;
    if (bid == 0 && t == 0) flag[0] = fl;

    if (bid < 135) {
        int gid = bid * 256 + t;
        if (gid < NCVT) {
            const void* srcp; int idx;
            if (gid < OB1) {
                if (gid < OW2)      { srcp = W1; idx = gid - OW1; }
                else if (gid < OWL) { srcp = W2; idx = gid - OW2; }
                else                { srcp = Wl; idx = gid - OWL; }
            } else {
                if (gid < OB2)      { srcp = b1; idx = gid - OB1; }
                else if (gid < OP)  { srcp = b2; idx = gid - OB2; }
                else if (gid < OBL) { srcp = p;  idx = gid - OP; }
                else                { srcp = bl; idx = gid - OBL; }
            }
            float v;
            if (gid >= OWL && gid < OB1 && idx >= 1280) v = 0.f;       // Wl pad
            else if (gid >= OBL && idx >= NC) v = 0.f;                  // bl pad
            else if (fl) v = bf2f(((const unsigned short*)srcp)[idx]);
            else v = ((const float*)srcp)[idx];
            cw[gid] = v;
            // bf16 transposed copies for the MFMA paths: w1t[n][k], w2t[n][k]
            if (gid < OW2) {
                int k = gid >> 7, n = gid & 127;
                w1t[n * 128 + k] = f2bf(v);
            } else if (gid < OWL) {
                int r = gid - OW2;
                int k = r >> 7, n = r & 127;
                w2t[n * 128 + k] = f2bf(v);
            }
        }
    } else if (bid == 135) {
        __shared__ float s2a[128];
        float pv = 0.f;
        if (t < 128) pv = fl ? bf2f(((const unsigned short*)p)[t]) : ((const float*)p)[t];
        if (t < 128) s2a[t] = pv * pv;
        __syncthreads();
        for (int off = 64; off; off >>= 1) {
            if (t < off) s2a[t] += s2a[t + off];
            __syncthreads();
        }
        if (t == 0) invnorm[0] = 1.0f / sqrtf(s2a[0]);
    } else if (bid < 392) {
        int i = (bid - 136) * 256 + t;
        new_id[i] = -1;
        if (i < NGRAPH) { ghist[i] = 0; gcur0[i] = 0; }
        if (i < NGRAPH * HD) pooled[i] = 0.f;
    } else {
        // ---- edge histogram partials ----
        if (t < NGRAPH) lh[t] = 0;
        __syncthreads();
        int e0 = (bid - 392) * 4096;
        for (int k = 0; k < 16; k++) atomicAdd(&lh[src[e0 + k * 256 + t] >> 10], 1);
        __syncthreads();
        if (t < NGRAPH) phist[(bid - 392) * 64 + t] = lh[t];
    }
}

// ---------------- edge binning by graph (reduces hist partials) --------------
__global__ __launch_bounds__(256) void binpass_kernel(const int* __restrict__ src,
                                                      const int* __restrict__ dst,
                                                      const int* __restrict__ phist,
                                                      int* __restrict__ ghist,
                                                      int* __restrict__ gcur0,
                                                      unsigned int* __restrict__ elist) {
    __shared__ int gh[NGRAPH];
    __shared__ int gbS[NGRAPH];
    __shared__ int lh[NGRAPH];
    __shared__ int lbase[NGRAPH];
    __shared__ int qsum[4][NGRAPH];
    int tid = threadIdx.x;
    {
        int g = tid & 63, q = tid >> 6;
        int s = 0;
        for (int b = q * 64; b < q * 64 + 64; b++) s += phist[b * 64 + g];
        qsum[q][g] = s;
    }
    __syncthreads();
    if (tid < NGRAPH) {
        gh[tid] = qsum[0][tid] + qsum[1][tid] + qsum[2][tid] + qsum[3][tid];
        lh[tid] = 0;
        if (blockIdx.x == 0) ghist[tid] = gh[tid];  // publish for downstream
    }
    __syncthreads();
    if (tid == 0) {
        int s = 0;
        for (int i = 0; i < NGRAPH; i++) { gbS[i] = s; s += gh[i]; }
    }
    __syncthreads();
    int e0 = blockIdx.x * 4096;  // 256 blocks
    int gs[16]; unsigned int pk[16];
    for (int k = 0; k < 16; k++) {
        int e = e0 + k * 256 + tid;
        int s = src[e], d = dst[e];
        gs[k] = s >> 10;
        pk[k] = (unsigned)(s & 1023) | ((unsigned)(d & 1023) << 10);
        atomicAdd(&lh[gs[k]], 1);
    }
    __syncthreads();
    if (tid < NGRAPH) { lbase[tid] = gbS[tid] + atomicAdd(&gcur0[tid], lh[tid]); lh[tid] = 0; }
    __syncthreads();
    for (int k = 0; k < 16; k++) {
        int g = gs[k];
        int pos = lbase[g] + atomicAdd(&lh[g], 1);
        elist[pos] = pk[k];
    }
}

// ---------------- FUSED: per-graph CSR counting-sort (blocks 0..63) ----------
// ---------------- + GEMM1 xw1 = A @ W1 via MFMA (blocks 64..319) ------------
__global__ __launch_bounds__(1024) void g1csr_kernel(
    const unsigned int* __restrict__ elist, const int* __restrict__ ghist,
    unsigned short* __restrict__ csr16, int* __restrict__ node_base,
    int* __restrict__ deg_out, float* __restrict__ dinv_out,
    const void* __restrict__ Araw, const unsigned short* __restrict__ Wtb,
    unsigned int* __restrict__ Cb, const int* __restrict__ flag) {
    __shared__ unsigned short sc[EMAX];  // 40 KB (csr path only)
    __shared__ int cnt[NPERG];           // 4 KB
    __shared__ int cur[NPERG];           // 4 KB
    __shared__ int wsum[16];
    __shared__ int gh[NGRAPH];
    __shared__ int baseS, nS;
    int bid = blockIdx.x, t = threadIdx.x;
    if (bid < NGRAPH) {
        int g = bid;
        cnt[t] = 0;
        if (t < NGRAPH) gh[t] = ghist[t];
        __syncthreads();
        if (t == 0) {
            int s = 0;
            for (int i = 0; i < g; i++) s += gh[i];
            baseS = s; nS = gh[g];
        }
        __syncthreads();
        int base = baseS;
        int n = nS; if (n > EMAX) n = EMAX;
        for (int j = t; j < n; j += 1024) atomicAdd(&cnt[(elist[base + j] >> 10) & 1023], 1);
        __syncthreads();
        int v = cnt[t];
        int lane = t & 63;
        int x = v;
        for (int off = 1; off < 64; off <<= 1) {
            int y = __shfl_up(x, off);
            if (lane >= off) x += y;
        }
        if (lane == 63) wsum[t >> 6] = x;
        __syncthreads();
        if (t < 16) {
            int wv = wsum[t];
            int wx = wv;
            for (int off = 1; off < 16; off <<= 1) {
                int y = __shfl_up(wx, off);
                if (t >= off) wx += y;
            }
            wsum[t] = wx - wv;  // exclusive wave base
        }
        __syncthreads();
        int excl = x - v + wsum[t >> 6];
        cur[t] = excl;
        deg_out[g * NPERG + t] = v;
        dinv_out[g * NPERG + t] = rsqrtf((float)v + 1.0f);
        node_base[g * NPERG + t] = base + excl;
        __syncthreads();
        for (int j = t; j < n; j += 1024) {
            unsigned int pk = elist[base + j];
            int d = (pk >> 10) & 1023;
            int pos = atomicAdd(&cur[d], 1);
            sc[pos] = (unsigned short)(pk & 1023);
        }
        __syncthreads();
        for (int j = t; j < n; j += 1024) csr16[base + j] = sc[j];
        return;
    }
    // ---- GEMM1 path: 16 waves/block, 16 rows/wave = 256 rows/block ----
    int row0 = (bid - NGRAPH) * 256;
    int wave = t >> 6, lane = t & 63;
    int r0 = row0 + wave * 16;
    int row = r0 + (lane & 15);
    int ko = (lane >> 4) * 8;                    // k offset within 32-chunk
    f32x4 acc[8];
#pragma unroll
    for (int c = 0; c < 8; c++) acc[c] = (f32x4){0.f, 0.f, 0.f, 0.f};
    bf16x8 afr[4];
    if (flag[0]) {
        const unsigned short* arow = (const unsigned short*)Araw + (size_t)row * HD + ko;
#pragma unroll
        for (int kk = 0; kk < 4; kk++) afr[kk] = *(const bf16x8*)(arow + kk * 32);
    } else {
        const float* arow = (const float*)Araw + (size_t)row * HD + ko;
#pragma unroll
        for (int kk = 0; kk < 4; kk++) {
            float4 f0 = *(const float4*)(arow + kk * 32);
            float4 f1 = *(const float4*)(arow + kk * 32 + 4);
            bf16x8 a;
            a[0] = (short)f2bf(f0.x); a[1] = (short)f2bf(f0.y);
            a[2] = (short)f2bf(f0.z); a[3] = (short)f2bf(f0.w);
            a[4] = (short)f2bf(f1.x); a[5] = (short)f2bf(f1.y);
            a[6] = (short)f2bf(f1.z); a[7] = (short)f2bf(f1.w);
            afr[kk] = a;
        }
    }
    const unsigned short* brow = Wtb + (lane & 15) * HD + ko;
#pragma unroll
    for (int kk = 0; kk < 4; kk++) {
#pragma unroll
        for (int c = 0; c < 8; c++) {
            bf16x8 b = *(const bf16x8*)(brow + c * 16 * HD + kk * 32);
            acc[c] = __builtin_amdgcn_mfma_f32_16x16x32_bf16(afr[kk], b, acc[c], 0, 0, 0);
        }
    }
    int orow0 = r0 + (lane >> 4) * 4;
    bool even = !(lane & 1);
#pragma unroll
    for (int c = 0; c < 8; c++) {
#pragma unroll
        for (int j = 0; j < 4; j++) {
            float v = acc[c][j];
            float pt = __shfl_xor(v, 1);
            if (even) {
                unsigned int u = (unsigned int)f2bf(v) | ((unsigned int)f2bf(pt) << 16);
                Cb[(size_t)(orow0 + j) * 64 + ((c * 16 + (lane & 15)) >> 1)] = u;
            }
        }
    }
}

// ---------------- conv1 aggregate (pull, 8-deep batched, bf16 rows) ----------
__global__ __launch_bounds__(256) void s1_pull(const unsigned short* __restrict__ csr16,
                                               const int* __restrict__ node_base,
                                               const int* __restrict__ deg,
                                               const float* __restrict__ dinv,
                                               const unsigned int* __restrict__ xwb,
                                               const float* __restrict__ b1,
                                               const float* __restrict__ pvec,
                                               const float* __restrict__ invnorm,
                                               unsigned int* __restrict__ hb,
                                               float* __restrict__ score) {
    int b = blockIdx.x;                 // 16384 blocks
    int xcd = b & 7, j = b >> 3;        // XCD-swizzle: graph pinned to one XCD
    int g = (j >> 8) * 8 + xcd;
    int n = g * NPERG + (j & 255) * 4 + (threadIdx.x >> 6);
    int lane = threadIdx.x & 63;
    int gb = g * NPERG;
    int base = node_base[n], cnt = deg[n];
    int e = 0; float ds = 0.f;
    if (lane < cnt) {
        e = csr16[base + lane];
        ds = dinv[gb + e];
    }
    float a0 = 0.f, a1 = 0.f;
    int klim = cnt < 64 ? cnt : 64;
    int k = 0;
    for (; k + 7 < klim; k += 8) {
        int s0 = __shfl(e, k),     s1 = __shfl(e, k + 1);
        int s2 = __shfl(e, k + 2), s3 = __shfl(e, k + 3);
        int s4 = __shfl(e, k + 4), s5 = __shfl(e, k + 5);
        int s6 = __shfl(e, k + 6), s7 = __shfl(e, k + 7);
        float d0 = __shfl(ds, k),     d1 = __shfl(ds, k + 1);
        float d2 = __shfl(ds, k + 2), d3 = __shfl(ds, k + 3);
        float d4 = __shfl(ds, k + 4), d5 = __shfl(ds, k + 5);
        float d6 = __shfl(ds, k + 6), d7 = __shfl(ds, k + 7);
        unsigned int u0 = xwb[(size_t)(gb + s0) * 64 + lane];
        unsigned int u1 = xwb[(size_t)(gb + s1) * 64 + lane];
        unsigned int u2 = xwb[(size_t)(gb + s2) * 64 + lane];
        unsigned int u3 = xwb[(size_t)(gb + s3) * 64 + lane];
        unsigned int u4 = xwb[(size_t)(gb + s4) * 64 + lane];
        unsigned int u5 = xwb[(size_t)(gb + s5) * 64 + lane];
        unsigned int u6 = xwb[(size_t)(gb + s6) * 64 + lane];
        unsigned int u7 = xwb[(size_t)(gb + s7) * 64 + lane];
        a0 += d0 * __uint_as_float(u0 << 16); a1 += d0 * __uint_as_float(u0 & 0xFFFF0000u);
        a0 += d1 * __uint_as_float(u1 << 16); a1 += d1 * __uint_as_float(u1 & 0xFFFF0000u);
        a0 += d2 * __uint_as_float(u2 << 16); a1 += d2 * __uint_as_float(u2 & 0xFFFF0000u);
        a0 += d3 * __uint_as_float(u3 << 16); a1 += d3 * __uint_as_float(u3 & 0xFFFF0000u);
        a0 += d4 * __uint_as_float(u4 << 16); a1 += d4 * __uint_as_float(u4 & 0xFFFF0000u);
        a0 += d5 * __uint_as_float(u5 << 16); a1 += d5 * __uint_as_float(u5 & 0xFFFF0000u);
        a0 += d6 * __uint_as_float(u6 << 16); a1 += d6 * __uint_as_float(u6 & 0xFFFF0000u);
        a0 += d7 * __uint_as_float(u7 << 16); a1 += d7 * __uint_as_float(u7 & 0xFFFF0000u);
    }
    for (; k + 3 < klim; k += 4) {
        int s0 = __shfl(e, k), s1 = __shfl(e, k + 1);
        int s2 = __shfl(e, k + 2), s3 = __shfl(e, k + 3);
        float d0 = __shfl(ds, k), d1 = __shfl(ds, k + 1);
        float d2 = __shfl(ds, k + 2), d3 = __shfl(ds, k + 3);
        unsigned int u0 = xwb[(size_t)(gb + s0) * 64 + lane];
        unsigned int u1 = xwb[(size_t)(gb + s1) * 64 + lane];
        unsigned int u2 = xwb[(size_t)(gb + s2) * 64 + lane];
        unsigned int u3 = xwb[(size_t)(gb + s3) * 64 + lane];
        a0 += d0 * __uint_as_float(u0 << 16); a1 += d0 * __uint_as_float(u0 & 0xFFFF0000u);
        a0 += d1 * __uint_as_float(u1 << 16); a1 += d1 * __uint_as_float(u1 & 0xFFFF0000u);
        a0 += d2 * __uint_as_float(u2 << 16); a1 += d2 * __uint_as_float(u2 & 0xFFFF0000u);
        a0 += d3 * __uint_as_float(u3 << 16); a1 += d3 * __uint_as_float(u3 & 0xFFFF0000u);
    }
    for (; k < klim; k++) {
        int sk = __shfl(e, k);
        float dk = __shfl(ds, k);
        unsigned int u = xwb[(size_t)(gb + sk) * 64 + lane];
        a0 += dk * __uint_as_float(u << 16); a1 += dk * __uint_as_float(u & 0xFFFF0000u);
    }
    for (; k < cnt; k++) {  // deg>64 cold path (P ~ 0, correctness only)
        int sk = csr16[base + k];
        float dk = dinv[gb + sk];
        unsigned int u = xwb[(size_t)(gb + sk) * 64 + lane];
        a0 += dk * __uint_as_float(u << 16); a1 += dk * __uint_as_float(u & 0xFFFF0000u);
    }
    float dn = dinv[n];
    float self = dn * dn;
    unsigned int us = xwb[(size_t)n * 64 + lane];
    float2 bb = ((const float2*)b1)[lane];
    float h0 = fmaxf(dn * a0 + self * __uint_as_float(us << 16) + bb.x, 0.f);
    float h1 = fmaxf(dn * a1 + self * __uint_as_float(us & 0xFFFF0000u) + bb.y, 0.f);
    hb[(size_t)n * 64 + lane] = (unsigned int)f2bf(h0) | ((unsigned int)f2bf(h1) << 16);
    float2 pp = ((const float2*)pvec)[lane];
    float sv = h0 * pp.x + h1 * pp.y;
    for (int off = 32; off; off >>= 1) sv += __shfl_down(sv, off);
    if (lane == 0) score[n] = tanhf(sv * invnorm[0]);
}

// ---------------- top-512 bitonic: register-resident, shuffle for j<64 -------
__global__ __launch_bounds__(1024) void topk_kernel(const float* __restrict__ score,
                                                    float* __restrict__ vals,
                                                    int* __restrict__ perm,
                                                    int* __restrict__ new_id) {
    __shared__ float sv[1024];
    __shared__ int si[1024];
    int g = blockIdx.x, t = threadIdx.x;
    float v = score[g * NPERG + t];
    int idx = t;
    for (int k = 2; k <= 1024; k <<= 1) {
        for (int j = k >> 1; j > 0; j >>= 1) {
            bool desc = ((t & k) == 0);
            bool up = (t & j) != 0;
            float vb; int ib;
            if (j >= 64) {
                sv[t] = v; si[t] = idx;
                __syncthreads();
                vb = sv[t ^ j]; ib = si[t ^ j];
                bool cmp = (v > vb) || (v == vb && idx < ib);  // lax.top_k tie rule
                bool keep = up ? (cmp != desc) : (cmp == desc);
                if (!keep) { v = vb; idx = ib; }
                __syncthreads();
            } else {
                vb = __shfl_xor(v, j);
                ib = __shfl_xor(idx, j);
                bool cmp = (v > vb) || (v == vb && idx < ib);
                bool keep = up ? (cmp != desc) : (cmp == desc);
                if (!keep) { v = vb; idx = ib; }
            }
        }
    }
    if (t < KEEP) {
        int node = g * NPERG + idx;
        int slot = g * KEEP + t;
        vals[slot] = v;
        perm[slot] = node;
        new_id[node] = slot;
    }
}

// ---------------- FUSED: deg2/dinv2 edge-pass (blocks 0..63) -----------------
// ---------------- + GEMM2 (vals*h[perm]) @ W2 MFMA, bf16-packed out ----------
__global__ __launch_bounds__(512) void g2deg_kernel(
    const unsigned int* __restrict__ elist, const int* __restrict__ ghist,
    const int* __restrict__ new_id, float* __restrict__ dinv2,
    const unsigned int* __restrict__ hb, const int* __restrict__ perm,
    const float* __restrict__ vals, const unsigned short* __restrict__ Wtb,
    unsigned int* __restrict__ Cb) {
    __shared__ int d2[KEEP];
    __shared__ int gh[NGRAPH];
    __shared__ int baseS, nS;
    int bid = blockIdx.x, t = threadIdx.x;
    if (bid < NGRAPH) {
        int g = bid;
        if (t < KEEP) d2[t] = 0;
        if (t < NGRAPH) gh[t] = ghist[t];
        __syncthreads();
        if (t == 0) {
            int s = 0;
            for (int i = 0; i < g; i++) s += gh[i];
            baseS = s; nS = gh[g];
        }
        __syncthreads();
        int base = baseS, n = nS;
        int gb = g * NPERG;
        int kb = g * KEEP;
        for (int j = t; j < n; j += 512) {
            unsigned int pk = elist[base + j];
            int s = pk & 1023, d = (pk >> 10) & 1023;
            int ns = new_id[gb + s], nd = new_id[gb + d];
            if (ns >= 0 && nd >= 0) atomicAdd(&d2[nd - kb], 1);
        }
        __syncthreads();
        if (t < KEEP) dinv2[kb + t] = rsqrtf((float)d2[t] + 1.0f);
        return;
    }
    // ---- GEMM2 path: 8 waves/block, 16 rows/wave = 128 rows/block ----
    int row0 = (bid - NGRAPH) * 128;
    int wave = t >> 6, lane = t & 63;
    int r0 = row0 + wave * 16;
    int m = r0 + (lane & 15);
    int ko = (lane >> 4) * 8;
    float sc = vals[m];
    const unsigned int* arow = hb + (size_t)perm[m] * 64 + (ko >> 1);
    bf16x8 afr[4];
#pragma unroll
    for (int kk = 0; kk < 4; kk++) {
        uint4 q = *(const uint4*)(arow + kk * 16);
        bf16x8 a;
        a[0] = (short)f2bf(bf2f((unsigned short)q.x) * sc);
        a[1] = (short)f2bf(bf2f((unsigned short)(q.x >> 16)) * sc);
        a[2] = (short)f2bf(bf2f((unsigned short)q.y) * sc);
        a[3] = (short)f2bf(bf2f((unsigned short)(q.y >> 16)) * sc);
        a[4] = (short)f2bf(bf2f((unsigned short)q.z) * sc);
        a[5] = (short)f2bf(bf2f((unsigned short)(q.z >> 16)) * sc);
        a[6] = (short)f2bf(bf2f((unsigned short)q.w) * sc);
        a[7] = (short)f2bf(bf2f((unsigned short)(q.w >> 16)) * sc);
        afr[kk] = a;
    }
    f32x4 acc[8];
#pragma unroll
    for (int c = 0; c < 8; c++) acc[c] = (f32x4){0.f, 0.f, 0.f, 0.f};
    const unsigned short* brow = Wtb + (lane & 15) * HD + ko;
#pragma unroll
    for (int kk = 0; kk < 4; kk++) {
#pragma unroll
        for (int c = 0; c < 8; c++) {
            bf16x8 b = *(const bf16x8*)(brow + c * 16 * HD + kk * 32);
            acc[c] = __builtin_amdgcn_mfma_f32_16x16x32_bf16(afr[kk], b, acc[c], 0, 0, 0);
        }
    }
    int orow0 = r0 + (lane >> 4) * 4;
    bool even = !(lane & 1);
#pragma unroll
    for (int c = 0; c < 8; c++) {
#pragma unroll
        for (int j = 0; j < 4; j++) {
            float v = acc[c][j];
            float pt = __shfl_xor(v, 1);
            if (even) {
                unsigned int u = (unsigned int)f2bf(v) | ((unsigned int)f2bf(pt) << 16);
                Cb[(size_t)(orow0 + j) * 64 + ((c * 16 + (lane & 15)) >> 1)] = u;
            }
        }
    }
}

// ---------------- conv2 aggregate: ballot-compact + bf16 rows + pool ---------
__global__ __launch_bounds__(256) void s2_pull(const unsigned short* __restrict__ csr16,
                                               const int* __restrict__ node_base,
                                               const int* __restrict__ deg,
                                               const int* __restrict__ perm,
                                               const int* __restrict__ new_id,
                                               const float* __restrict__ dinv2,
                                               const unsigned int* __restrict__ xwb2,
                                               const float* __restrict__ b2,
                                               float* __restrict__ pooled) {
    __shared__ float pr[HD];
    __shared__ int cnk[4][64];
    __shared__ float cds[4][64];
    int tid = threadIdx.x;
    if (tid < HD) pr[tid] = 0.f;
    __syncthreads();
    int b = blockIdx.x;              // 8192 blocks
    int xcd = b & 7, j = b >> 3;
    int g = (j >> 7) * 8 + xcd;
    int wv = tid >> 6;
    int m = g * KEEP + (j & 127) * 4 + wv;
    int lane = tid & 63;
    int node = perm[m];
    int gb = node & ~(NPERG - 1);
    int base = node_base[node], cnt = deg[node];
    int nk = 0; float ds = 0.f;
    if (lane < cnt) {
        int ns = new_id[gb + csr16[base + lane]];
        if (ns >= 0) { nk = ns; ds = dinv2[ns]; }
    }
    // ballot-compact survivors into per-wave LDS (ascending lane order)
    unsigned long long msk = __ballot(ds != 0.f);
    int pos = __popcll(msk & ((1ull << lane) - 1ull));
    if (ds != 0.f) { cnk[wv][pos] = nk; cds[wv][pos] = ds; }
    int na = __popcll(msk);
    float a0 = 0.f, a1 = 0.f;
    int k = 0;
    for (; k + 7 < na; k += 8) {
        int s0 = cnk[wv][k],     s1 = cnk[wv][k + 1];
        int s2 = cnk[wv][k + 2], s3 = cnk[wv][k + 3];
        int s4 = cnk[wv][k + 4], s5 = cnk[wv][k + 5];
        int s6 = cnk[wv][k + 6], s7 = cnk[wv][k + 7];
        float d0 = cds[wv][k],     d1 = cds[wv][k + 1];
        float d2 = cds[wv][k + 2], d3 = cds[wv][k + 3];
        float d4 = cds[wv][k + 4], d5 = cds[wv][k + 5];
        float d6 = cds[wv][k + 6], d7 = cds[wv][k + 7];
        unsigned int u0 = xwb2[(size_t)s0 * 64 + lane];
        unsigned int u1 = xwb2[(size_t)s1 * 64 + lane];
        unsigned int u2 = xwb2[(size_t)s2 * 64 + lane];
        unsigned int u3 = xwb2[(size_t)s3 * 64 + lane];
        unsigned int u4 = xwb2[(size_t)s4 * 64 + lane];
        unsigned int u5 = xwb2[(size_t)s5 * 64 + lane];
        unsigned int u6 = xwb2[(size_t)s6 * 64 + lane];
        unsigned int u7 = xwb2[(size_t)s7 * 64 + lane];
        a0 += d0 * __uint_as_float(u0 << 16); a1 += d0 * __uint_as_float(u0 & 0xFFFF0000u);
        a0 += d1 * __uint_as_float(u1 << 16); a1 += d1 * __uint_as_float(u1 & 0xFFFF0000u);
        a0 += d2 * __uint_as_float(u2 << 16); a1 += d2 * __uint_as_float(u2 & 0xFFFF0000u);
        a0 += d3 * __uint_as_float(u3 << 16); a1 += d3 * __uint_as_float(u3 & 0xFFFF0000u);
        a0 += d4 * __uint_as_float(u4 << 16); a1 += d4 * __uint_as_float(u4 & 0xFFFF0000u);
        a0 += d5 * __uint_as_float(u5 << 16); a1 += d5 * __uint_as_float(u5 & 0xFFFF0000u);
        a0 += d6 * __uint_as_float(u6 << 16); a1 += d6 * __uint_as_float(u6 & 0xFFFF0000u);
        a0 += d7 * __uint_as_float(u7 << 16); a1 += d7 * __uint_as_float(u7 & 0xFFFF0000u);
    }
    for (; k + 3 < na; k += 4) {
        int s0 = cnk[wv][k], s1 = cnk[wv][k + 1];
        int s2 = cnk[wv][k + 2], s3 = cnk[wv][k + 3];
        float d0 = cds[wv][k], d1 = cds[wv][k + 1];
        float d2 = cds[wv][k + 2], d3 = cds[wv][k + 3];
        unsigned int u0 = xwb2[(size_t)s0 * 64 + lane];
        unsigned int u1 = xwb2[(size_t)s1 * 64 + lane];
        unsigned int u2 = xwb2[(size_t)s2 * 64 + lane];
        unsigned int u3 = xwb2[(size_t)s3 * 64 + lane];
        a0 += d0 * __uint_as_float(u0 << 16); a1 += d0 * __uint_as_float(u0 & 0xFFFF0000u);
        a0 += d1 * __uint_as_float(u1 << 16); a1 += d1 * __uint_as_float(u1 & 0xFFFF0000u);
        a0 += d2 * __uint_as_float(u2 << 16); a1 += d2 * __uint_as_float(u2 & 0xFFFF0000u);
        a0 += d3 * __uint_as_float(u3 << 16); a1 += d3 * __uint_as_float(u3 & 0xFFFF0000u);
    }
    for (; k < na; k++) {
        int sk = cnk[wv][k];
        float dk = cds[wv][k];
        unsigned int u = xwb2[(size_t)sk * 64 + lane];
        a0 += dk * __uint_as_float(u << 16); a1 += dk * __uint_as_float(u & 0xFFFF0000u);
    }
    for (int kk = 64; kk < cnt; kk++) {    // deg>64 cold path
        int ns = new_id[gb + csr16[base + kk]];
        if (ns >= 0) {
            float dk = dinv2[ns];
            unsigned int u = xwb2[(size_t)ns * 64 + lane];
            a0 += dk * __uint_as_float(u << 16); a1 += dk * __uint_as_float(u & 0xFFFF0000u);
        }
    }
    float dn = dinv2[m];
    float self = dn * dn;
    unsigned int us = xwb2[(size_t)m * 64 + lane];
    float2 bb = ((const float2*)b2)[lane];
    float o0 = fmaxf(dn * a0 + self * __uint_as_float(us << 16) + bb.x, 0.f);
    float o1 = fmaxf(dn * a1 + self * __uint_as_float(us & 0xFFFF0000u) + bb.y, 0.f);
    atomicAdd(&pr[lane * 2], o0);
    atomicAdd(&pr[lane * 2 + 1], o1);
    __syncthreads();
    if (tid < HD) atomicAdd(&pooled[g * HD + tid], pr[tid]);
}

// ---------------- final linear: out = (pooled/512) @ Wl + bl -----------------
__global__ __launch_bounds__(128) void outk_kernel(const float* __restrict__ pooled,
                                                   const float* __restrict__ Wl,
                                                   const float* __restrict__ bl,
                                                   void* __restrict__ outv,
                                                   const int* __restrict__ flag) {
    int g = blockIdx.x, t = threadIdx.x;  // 128
    __shared__ float sp[HD];
    sp[t] = pooled[g * HD + t] * (1.0f / KEEP);
    __syncthreads();
    if (t < NC) {
        float acc = bl[t];
        for (int hh = 0; hh < HD; hh++) acc += sp[hh] * Wl[hh * NC + t];
        if (flag[0]) ((unsigned short*)outv)[g * NC + t] = f2bf(acc);
        else         ((float*)outv)[g * NC + t] = acc;
    }
}

extern "C" void kernel_launch(void* const* d_in, const int* in_sizes, int n_in,
                              void* d_out, int out_size, void* d_ws, size_t ws_size,
                              hipStream_t stream) {
    const int* ei   = (const int*)d_in[1];
    const int* srcv = ei;
    const int* dstv = ei + NEDGES;

    char* w = (char*)d_ws;
    const size_t MB = 1u << 20;
    const size_t KB = 1024;
    float* dinv1     = (float*)(w + 0);                 // 256 KB
    float* score     = (float*)(w + 256 * KB);          // 256 KB
    float* vals      = (float*)(w + 512 * KB);          // 128 KB
    int*   perm      = (int*)(w + 640 * KB);            // 128 KB
    int*   new_id    = (int*)(w + 768 * KB);            // 256 KB
    int*   deg1      = (int*)(w + 1024 * KB);           // 256 KB
    int*   node_base = (int*)(w + 1280 * KB);           // 256 KB
    float* dinv2     = (float*)(w + 1536 * KB);         // 128 KB
    float* invnorm   = (float*)(w + 1664 * KB);
    int*   flag      = (int*)(w + 1664 * KB + 64);
    int*   ghist     = (int*)(w + 1664 * KB + 1024);
    int*   gcur0     = (int*)(w + 1664 * KB + 2048);
    float* cw        = (float*)(w + 1700 * KB);         // 135 KB canonical weights
    float* pooled    = (float*)(w + 1840 * KB);         // 32 KB
    unsigned short* w1t = (unsigned short*)(w + 1880 * KB);  // 32 KB bf16 W1^T
    unsigned short* w2t = (unsigned short*)(w + 1912 * KB);  // 32 KB bf16 W2^T
    int* phist       = (int*)(w + 1944 * KB);           // 64 KB hist partials
    unsigned int* xw1b = (unsigned int*)(w + 2 * MB);   // [2,18) MB  bf16-packed xw1
    unsigned int* xw2b = (unsigned int*)(w + 18 * MB);  // [18,26) MB bf16-packed xw2
    unsigned int* hb = (unsigned int*)(w + 34 * MB);    // [34,50) MB bf16-packed h
    unsigned int* elist    = (unsigned int*)(w + 66 * MB);   // [66,70) MB
    unsigned short* csr16  = (unsigned short*)(w + 70 * MB); // [70,72) MB

    float* W1f = cw + OW1; float* W2f = cw + OW2; float* Wlf = cw + OWL;
    float* b1f = cw + OB1; float* b2f = cw + OB2; float* pf  = cw + OP;
    float* blf = cw + OBL;
    (void)W1f; (void)W2f;

    prep_kernel<<<648, 256, 0, stream>>>(d_in[3], d_in[4], d_in[5], d_in[6], d_in[7],
                                         d_in[8], d_in[9], flag, cw, invnorm, new_id,
                                         ghist, gcur0, pooled, w1t, w2t, srcv, phist);
    binpass_kernel<<<256, 256, 0, stream>>>(srcv, dstv, phist, ghist, gcur0, elist);
    g1csr_kernel<<<NGRAPH + NNODES / 256, 1024, 0, stream>>>(
        elist, ghist, csr16, node_base, deg1, dinv1, d_in[0], w1t, xw1b, flag);
    s1_pull<<<NNODES / 4, 256, 0, stream>>>(csr16, node_base, deg1, dinv1, xw1b, b1f, pf,
                                            invnorm, hb, score);
    topk_kernel<<<NGRAPH, 1024, 0, stream>>>(score, vals, perm, new_id);
    g2deg_kernel<<<NGRAPH + M2 / 128, 512, 0, stream>>>(
        elist, ghist, new_id, dinv2, hb, perm, vals, w2t, xw2b);
    s2_pull<<<M2 / 4, 256, 0, stream>>>(csr16, node_base, deg1, perm, new_id, dinv2,
                                        xw2b, b2f, pooled);
    outk_kernel<<<NGRAPH, 128, 0, stream>>>(pooled, Wlf, blf, d_out, flag);

    (void)in_sizes; (void)n_in; (void)out_size; (void)ws_size;
}

// Round 10
// 243.837 us; speedup vs baseline: 1.2971x; 1.0545x over previous
//
#include <hip/hip_runtime.h>

#define NNODES 65536
#define NEDGES 1048576
#define NGRAPH 64
#define NPERG  1024
#define KEEP   512
#define M2     (NGRAPH * KEEP)   // 32768
#define HD     128
#define NC     10
#define EMAX   20480             // per-graph edge capacity (avg 16384, sigma~127)

// canonical weight block offsets (floats)
#define OW1 0
#define OW2 16384
#define OWL 32768
#define OB1 34048
#define OB2 34176
#define OP  34304
#define OBL 34432
#define NCVT 34448

typedef __attribute__((ext_vector_type(8))) short bf16x8;
typedef __attribute__((ext_vector_type(4))) float f32x4;

__device__ __forceinline__ float bf2f(unsigned short u) {
    return __uint_as_float(((unsigned int)u) << 16);
}
__device__ __forceinline__ unsigned short f2bf(float f) {
    unsigned int u = __float_as_uint(f);
    unsigned int r = (u + 0x7FFFu + ((u >> 16) & 1u)) >> 16;
    return (unsigned short)r;
}

// ------- prep: detect dtype + cvt weights + pnorm + init + edge binning ------
// Blocks [0,135): weight cvt; 135: pnorm; [136,392): init; [392,648): edge
// binning straight into fixed-stride per-graph elist regions (g*EMAX) via
// per-block LDS hist + one global reservation per graph (gcur0). Single pass
// over the edge list; ghist accumulated atomically. gcur0/ghist zeroed by a
// memsetAsync BEFORE this kernel (same-kernel init would race with binning).
__global__ __launch_bounds__(256) void prep_kernel(
    const void* __restrict__ W1, const void* __restrict__ b1, const void* __restrict__ p,
    const void* __restrict__ W2, const void* __restrict__ b2, const void* __restrict__ Wl,
    const void* __restrict__ bl, int* __restrict__ flag, float* __restrict__ cw,
    float* __restrict__ invnorm, int* __restrict__ new_id, int* __restrict__ ghist,
    int* __restrict__ gcur0, float* __restrict__ pooled,
    unsigned short* __restrict__ w1t, unsigned short* __restrict__ w2t,
    const int* __restrict__ src, const int* __restrict__ dst,
    unsigned int* __restrict__ elist) {
    int bid = blockIdx.x, t = threadIdx.x;
    const unsigned short* w1u = (const unsigned short*)W1;
    int local = 0;
    for (int i = t; i < 512; i += 256) {
        unsigned short u = w1u[2 * i];
        int e = (u >> 7) & 0xFF;
        local += (e >= 100 && e <= 140) ? 1 : 0;
    }
    __shared__ int red[256];
    __shared__ int lh[NGRAPH];
    __shared__ int lbase[NGRAPH];
    red[t] = local;
    __syncthreads();
    for (int off = 128; off; off >>= 1) {
        if (t < off) red[t] += red[t + off];
        __syncthreads();
    }
    int fl = (red[0] >= 384) ? 1 : 0;
    if (bid == 0 && t == 0) flag[0] = fl;

    if (bid < 135) {
        int gid = bid * 256 + t;
        if (gid < NCVT) {
            const void* srcp; int idx;
            if (gid < OB1) {
                if (gid < OW2)      { srcp = W1; idx = gid - OW1; }
                else if (gid < OWL) { srcp = W2; idx = gid - OW2; }
                else                { srcp = Wl; idx = gid - OWL; }
            } else {
                if (gid < OB2)      { srcp = b1; idx = gid - OB1; }
                else if (gid < OP)  { srcp = b2; idx = gid - OB2; }
                else if (gid < OBL) { srcp = p;  idx = gid - OP; }
                else                { srcp = bl; idx = gid - OBL; }
            }
            float v;
            if (gid >= OWL && gid < OB1 && idx >= 1280) v = 0.f;       // Wl pad
            else if (gid >= OBL && idx >= NC) v = 0.f;                  // bl pad
            else if (fl) v = bf2f(((const unsigned short*)srcp)[idx]);
            else v = ((const float*)srcp)[idx];
            cw[gid] = v;
            // bf16 transposed copies for the MFMA paths: w1t[n][k], w2t[n][k]
            if (gid < OW2) {
                int k = gid >> 7, n = gid & 127;
                w1t[n * 128 + k] = f2bf(v);
            } else if (gid < OWL) {
                int r = gid - OW2;
                int k = r >> 7, n = r & 127;
                w2t[n * 128 + k] = f2bf(v);
            }
        }
    } else if (bid == 135) {
        __shared__ float s2a[128];
        float pv = 0.f;
        if (t < 128) pv = fl ? bf2f(((const unsigned short*)p)[t]) : ((const float*)p)[t];
        if (t < 128) s2a[t] = pv * pv;
        __syncthreads();
        for (int off = 64; off; off >>= 1) {
            if (t < off) s2a[t] += s2a[t + off];
            __syncthreads();
        }
        if (t == 0) invnorm[0] = 1.0f / sqrtf(s2a[0]);
    } else if (bid < 392) {
        int i = (bid - 136) * 256 + t;
        new_id[i] = -1;
        if (i < NGRAPH * HD) pooled[i] = 0.f;
    } else {
        // ---- edge binning into fixed-stride regions (was binpass) ----
        if (t < NGRAPH) lh[t] = 0;
        __syncthreads();
        int e0 = (bid - 392) * 4096;  // 256 blocks x 4096 edges
        int gs[16]; unsigned int pk[16];
        for (int k = 0; k < 16; k++) {
            int e = e0 + k * 256 + t;
            int s = src[e], d = dst[e];
            gs[k] = s >> 10;
            pk[k] = (unsigned)(s & 1023) | ((unsigned)(d & 1023) << 10);
            atomicAdd(&lh[gs[k]], 1);
        }
        __syncthreads();
        if (t < NGRAPH) {
            int c = lh[t];
            lbase[t] = atomicAdd(&gcur0[t], c);
            atomicAdd(&ghist[t], c);
            lh[t] = 0;
        }
        __syncthreads();
        for (int k = 0; k < 16; k++) {
            int g = gs[k];
            int pos = lbase[g] + atomicAdd(&lh[g], 1);
            if (pos < EMAX) elist[g * EMAX + pos] = pk[k];
        }
    }
}

// ---------------- FUSED: per-graph CSR counting-sort (blocks 0..63) ----------
// ---------------- + GEMM1 xw1 = A @ W1 via MFMA (blocks 64..319) ------------
// Fixed-stride elist regions: base = g*EMAX, no prefix scan needed.
__global__ __launch_bounds__(1024) void g1csr_kernel(
    const unsigned int* __restrict__ elist, const int* __restrict__ ghist,
    unsigned short* __restrict__ csr16, int* __restrict__ node_base,
    int* __restrict__ deg_out, float* __restrict__ dinv_out,
    const void* __restrict__ Araw, const unsigned short* __restrict__ Wtb,
    unsigned int* __restrict__ Cb, const int* __restrict__ flag) {
    __shared__ unsigned short sc[EMAX];  // 40 KB (csr path only)
    __shared__ int cnt[NPERG];           // 4 KB
    __shared__ int cur[NPERG];           // 4 KB
    __shared__ int wsum[16];
    int bid = blockIdx.x, t = threadIdx.x;
    if (bid < NGRAPH) {
        int g = bid;
        cnt[t] = 0;
        __syncthreads();
        int base = g * EMAX;
        int n = ghist[g]; if (n > EMAX) n = EMAX;
        for (int j = t; j < n; j += 1024) atomicAdd(&cnt[(elist[base + j] >> 10) & 1023], 1);
        __syncthreads();
        int v = cnt[t];
        int lane = t & 63;
        int x = v;
        for (int off = 1; off < 64; off <<= 1) {
            int y = __shfl_up(x, off);
            if (lane >= off) x += y;
        }
        if (lane == 63) wsum[t >> 6] = x;
        __syncthreads();
        if (t < 16) {
            int wv = wsum[t];
            int wx = wv;
            for (int off = 1; off < 16; off <<= 1) {
                int y = __shfl_up(wx, off);
                if (t >= off) wx += y;
            }
            wsum[t] = wx - wv;  // exclusive wave base
        }
        __syncthreads();
        int excl = x - v + wsum[t >> 6];
        cur[t] = excl;
        deg_out[g * NPERG + t] = v;
        dinv_out[g * NPERG + t] = rsqrtf((float)v + 1.0f);
        node_base[g * NPERG + t] = base + excl;
        __syncthreads();
        for (int j = t; j < n; j += 1024) {
            unsigned int pk = elist[base + j];
            int d = (pk >> 10) & 1023;
            int pos = atomicAdd(&cur[d], 1);
            sc[pos] = (unsigned short)(pk & 1023);
        }
        __syncthreads();
        for (int j = t; j < n; j += 1024) csr16[base + j] = sc[j];
        return;
    }
    // ---- GEMM1 path: 16 waves/block, 16 rows/wave = 256 rows/block ----
    int row0 = (bid - NGRAPH) * 256;
    int wave = t >> 6, lane = t & 63;
    int r0 = row0 + wave * 16;
    int row = r0 + (lane & 15);
    int ko = (lane >> 4) * 8;                    // k offset within 32-chunk
    f32x4 acc[8];
#pragma unroll
    for (int c = 0; c < 8; c++) acc[c] = (f32x4){0.f, 0.f, 0.f, 0.f};
    bf16x8 afr[4];
    if (flag[0]) {
        const unsigned short* arow = (const unsigned short*)Araw + (size_t)row * HD + ko;
#pragma unroll
        for (int kk = 0; kk < 4; kk++) afr[kk] = *(const bf16x8*)(arow + kk * 32);
    } else {
        const float* arow = (const float*)Araw + (size_t)row * HD + ko;
#pragma unroll
        for (int kk = 0; kk < 4; kk++) {
            float4 f0 = *(const float4*)(arow + kk * 32);
            float4 f1 = *(const float4*)(arow + kk * 32 + 4);
            bf16x8 a;
            a[0] = (short)f2bf(f0.x); a[1] = (short)f2bf(f0.y);
            a[2] = (short)f2bf(f0.z); a[3] = (short)f2bf(f0.w);
            a[4] = (short)f2bf(f1.x); a[5] = (short)f2bf(f1.y);
            a[6] = (short)f2bf(f1.z); a[7] = (short)f2bf(f1.w);
            afr[kk] = a;
        }
    }
    const unsigned short* brow = Wtb + (lane & 15) * HD + ko;
#pragma unroll
    for (int kk = 0; kk < 4; kk++) {
#pragma unroll
        for (int c = 0; c < 8; c++) {
            bf16x8 b = *(const bf16x8*)(brow + c * 16 * HD + kk * 32);
            acc[c] = __builtin_amdgcn_mfma_f32_16x16x32_bf16(afr[kk], b, acc[c], 0, 0, 0);
        }
    }
    int orow0 = r0 + (lane >> 4) * 4;
    bool even = !(lane & 1);
#pragma unroll
    for (int c = 0; c < 8; c++) {
#pragma unroll
        for (int j = 0; j < 4; j++) {
            float v = acc[c][j];
            float pt = __shfl_xor(v, 1);
            if (even) {
                unsigned int u = (unsigned int)f2bf(v) | ((unsigned int)f2bf(pt) << 16);
                Cb[(size_t)(orow0 + j) * 64 + ((c * 16 + (lane & 15)) >> 1)] = u;
            }
        }
    }
}

// ---------------- conv1 aggregate (pull, 8-deep batched, bf16 rows) ----------
__global__ __launch_bounds__(256) void s1_pull(const unsigned short* __restrict__ csr16,
                                               const int* __restrict__ node_base,
                                               const int* __restrict__ deg,
                                               const float* __restrict__ dinv,
                                               const unsigned int* __restrict__ xwb,
                                               const float* __restrict__ b1,
                                               const float* __restrict__ pvec,
                                               const float* __restrict__ invnorm,
                                               unsigned int* __restrict__ hb,
                                               float* __restrict__ score) {
    int b = blockIdx.x;                 // 16384 blocks
    int xcd = b & 7, j = b >> 3;        // XCD-swizzle: graph pinned to one XCD
    int g = (j >> 8) * 8 + xcd;
    int n = g * NPERG + (j & 255) * 4 + (threadIdx.x >> 6);
    int lane = threadIdx.x & 63;
    int gb = g * NPERG;
    int base = node_base[n], cnt = deg[n];
    int e = 0; float ds = 0.f;
    if (lane < cnt) {
        e = csr16[base + lane];
        ds = dinv[gb + e];
    }
    float a0 = 0.f, a1 = 0.f;
    int klim = cnt < 64 ? cnt : 64;
    int k = 0;
    for (; k + 7 < klim; k += 8) {
        int s0 = __shfl(e, k),     s1 = __shfl(e, k + 1);
        int s2 = __shfl(e, k + 2), s3 = __shfl(e, k + 3);
        int s4 = __shfl(e, k + 4), s5 = __shfl(e, k + 5);
        int s6 = __shfl(e, k + 6), s7 = __shfl(e, k + 7);
        float d0 = __shfl(ds, k),     d1 = __shfl(ds, k + 1);
        float d2 = __shfl(ds, k + 2), d3 = __shfl(ds, k + 3);
        float d4 = __shfl(ds, k + 4), d5 = __shfl(ds, k + 5);
        float d6 = __shfl(ds, k + 6), d7 = __shfl(ds, k + 7);
        unsigned int u0 = xwb[(size_t)(gb + s0) * 64 + lane];
        unsigned int u1 = xwb[(size_t)(gb + s1) * 64 + lane];
        unsigned int u2 = xwb[(size_t)(gb + s2) * 64 + lane];
        unsigned int u3 = xwb[(size_t)(gb + s3) * 64 + lane];
        unsigned int u4 = xwb[(size_t)(gb + s4) * 64 + lane];
        unsigned int u5 = xwb[(size_t)(gb + s5) * 64 + lane];
        unsigned int u6 = xwb[(size_t)(gb + s6) * 64 + lane];
        unsigned int u7 = xwb[(size_t)(gb + s7) * 64 + lane];
        a0 += d0 * __uint_as_float(u0 << 16); a1 += d0 * __uint_as_float(u0 & 0xFFFF0000u);
        a0 += d1 * __uint_as_float(u1 << 16); a1 += d1 * __uint_as_float(u1 & 0xFFFF0000u);
        a0 += d2 * __uint_as_float(u2 << 16); a1 += d2 * __uint_as_float(u2 & 0xFFFF0000u);
        a0 += d3 * __uint_as_float(u3 << 16); a1 += d3 * __uint_as_float(u3 & 0xFFFF0000u);
        a0 += d4 * __uint_as_float(u4 << 16); a1 += d4 * __uint_as_float(u4 & 0xFFFF0000u);
        a0 += d5 * __uint_as_float(u5 << 16); a1 += d5 * __uint_as_float(u5 & 0xFFFF0000u);
        a0 += d6 * __uint_as_float(u6 << 16); a1 += d6 * __uint_as_float(u6 & 0xFFFF0000u);
        a0 += d7 * __uint_as_float(u7 << 16); a1 += d7 * __uint_as_float(u7 & 0xFFFF0000u);
    }
    for (; k + 3 < klim; k += 4) {
        int s0 = __shfl(e, k), s1 = __shfl(e, k + 1);
        int s2 = __shfl(e, k + 2), s3 = __shfl(e, k + 3);
        float d0 = __shfl(ds, k), d1 = __shfl(ds, k + 1);
        float d2 = __shfl(ds, k + 2), d3 = __shfl(ds, k + 3);
        unsigned int u0 = xwb[(size_t)(gb + s0) * 64 + lane];
        unsigned int u1 = xwb[(size_t)(gb + s1) * 64 + lane];
        unsigned int u2 = xwb[(size_t)(gb + s2) * 64 + lane];
        unsigned int u3 = xwb[(size_t)(gb + s3) * 64 + lane];
        a0 += d0 * __uint_as_float(u0 << 16); a1 += d0 * __uint_as_float(u0 & 0xFFFF0000u);
        a0 += d1 * __uint_as_float(u1 << 16); a1 += d1 * __uint_as_float(u1 & 0xFFFF0000u);
        a0 += d2 * __uint_as_float(u2 << 16); a1 += d2 * __uint_as_float(u2 & 0xFFFF0000u);
        a0 += d3 * __uint_as_float(u3 << 16); a1 += d3 * __uint_as_float(u3 & 0xFFFF0000u);
    }
    for (; k < klim; k++) {
        int sk = __shfl(e, k);
        float dk = __shfl(ds, k);
        unsigned int u = xwb[(size_t)(gb + sk) * 64 + lane];
        a0 += dk * __uint_as_float(u << 16); a1 += dk * __uint_as_float(u & 0xFFFF0000u);
    }
    for (; k < cnt; k++) {  // deg>64 cold path (P ~ 0, correctness only)
        int sk = csr16[base + k];
        float dk = dinv[gb + sk];
        unsigned int u = xwb[(size_t)(gb + sk) * 64 + lane];
        a0 += dk * __uint_as_float(u << 16); a1 += dk * __uint_as_float(u & 0xFFFF0000u);
    }
    float dn = dinv[n];
    float self = dn * dn;
    unsigned int us = xwb[(size_t)n * 64 + lane];
    float2 bb = ((const float2*)b1)[lane];
    float h0 = fmaxf(dn * a0 + self * __uint_as_float(us << 16) + bb.x, 0.f);
    float h1 = fmaxf(dn * a1 + self * __uint_as_float(us & 0xFFFF0000u) + bb.y, 0.f);
    hb[(size_t)n * 64 + lane] = (unsigned int)f2bf(h0) | ((unsigned int)f2bf(h1) << 16);
    float2 pp = ((const float2*)pvec)[lane];
    float sv = h0 * pp.x + h1 * pp.y;
    for (int off = 32; off; off >>= 1) sv += __shfl_down(sv, off);
    if (lane == 0) score[n] = tanhf(sv * invnorm[0]);
}

// ---------------- top-512 bitonic: register-resident, shuffle for j<64 -------
__global__ __launch_bounds__(1024) void topk_kernel(const float* __restrict__ score,
                                                    float* __restrict__ vals,
                                                    int* __restrict__ perm,
                                                    int* __restrict__ new_id) {
    __shared__ float sv[1024];
    __shared__ int si[1024];
    int g = blockIdx.x, t = threadIdx.x;
    float v = score[g * NPERG + t];
    int idx = t;
    for (int k = 2; k <= 1024; k <<= 1) {
        for (int j = k >> 1; j > 0; j >>= 1) {
            bool desc = ((t & k) == 0);
            bool up = (t & j) != 0;
            float vb; int ib;
            if (j >= 64) {
                sv[t] = v; si[t] = idx;
                __syncthreads();
                vb = sv[t ^ j]; ib = si[t ^ j];
                bool cmp = (v > vb) || (v == vb && idx < ib);  // lax.top_k tie rule
                bool keep = up ? (cmp != desc) : (cmp == desc);
                if (!keep) { v = vb; idx = ib; }
                __syncthreads();
            } else {
                vb = __shfl_xor(v, j);
                ib = __shfl_xor(idx, j);
                bool cmp = (v > vb) || (v == vb && idx < ib);
                bool keep = up ? (cmp != desc) : (cmp == desc);
                if (!keep) { v = vb; idx = ib; }
            }
        }
    }
    if (t < KEEP) {
        int node = g * NPERG + idx;
        int slot = g * KEEP + t;
        vals[slot] = v;
        perm[slot] = node;
        new_id[node] = slot;
    }
}

// ---------------- FUSED: deg2/dinv2 edge-pass (blocks 0..63) -----------------
// ---------------- + GEMM2 (vals*h[perm]) @ W2 MFMA, bf16-packed out ----------
__global__ __launch_bounds__(512) void g2deg_kernel(
    const unsigned int* __restrict__ elist, const int* __restrict__ ghist,
    const int* __restrict__ new_id, float* __restrict__ dinv2,
    const unsigned int* __restrict__ hb, const int* __restrict__ perm,
    const float* __restrict__ vals, const unsigned short* __restrict__ Wtb,
    unsigned int* __restrict__ Cb) {
    __shared__ int d2[KEEP];
    int bid = blockIdx.x, t = threadIdx.x;
    if (bid < NGRAPH) {
        int g = bid;
        if (t < KEEP) d2[t] = 0;
        __syncthreads();
        int base = g * EMAX;
        int n = ghist[g]; if (n > EMAX) n = EMAX;
        int gb = g * NPERG;
        int kb = g * KEEP;
        for (int j = t; j < n; j += 512) {
            unsigned int pk = elist[base + j];
            int s = pk & 1023, d = (pk >> 10) & 1023;
            int ns = new_id[gb + s], nd = new_id[gb + d];
            if (ns >= 0 && nd >= 0) atomicAdd(&d2[nd - kb], 1);
        }
        __syncthreads();
        if (t < KEEP) dinv2[kb + t] = rsqrtf((float)d2[t] + 1.0f);
        return;
    }
    // ---- GEMM2 path: 8 waves/block, 16 rows/wave = 128 rows/block ----
    int row0 = (bid - NGRAPH) * 128;
    int wave = t >> 6, lane = t & 63;
    int r0 = row0 + wave * 16;
    int m = r0 + (lane & 15);
    int ko = (lane >> 4) * 8;
    float sc = vals[m];
    const unsigned int* arow = hb + (size_t)perm[m] * 64 + (ko >> 1);
    bf16x8 afr[4];
#pragma unroll
    for (int kk = 0; kk < 4; kk++) {
        uint4 q = *(const uint4*)(arow + kk * 16);
        bf16x8 a;
        a[0] = (short)f2bf(bf2f((unsigned short)q.x) * sc);
        a[1] = (short)f2bf(bf2f((unsigned short)(q.x >> 16)) * sc);
        a[2] = (short)f2bf(bf2f((unsigned short)q.y) * sc);
        a[3] = (short)f2bf(bf2f((unsigned short)(q.y >> 16)) * sc);
        a[4] = (short)f2bf(bf2f((unsigned short)q.z) * sc);
        a[5] = (short)f2bf(bf2f((unsigned short)(q.z >> 16)) * sc);
        a[6] = (short)f2bf(bf2f((unsigned short)q.w) * sc);
        a[7] = (short)f2bf(bf2f((unsigned short)(q.w >> 16)) * sc);
        afr[kk] = a;
    }
    f32x4 acc[8];
#pragma unroll
    for (int c = 0; c < 8; c++) acc[c] = (f32x4){0.f, 0.f, 0.f, 0.f};
    const unsigned short* brow = Wtb + (lane & 15) * HD + ko;
#pragma unroll
    for (int kk = 0; kk < 4; kk++) {
#pragma unroll
        for (int c = 0; c < 8; c++) {
            bf16x8 b = *(const bf16x8*)(brow + c * 16 * HD + kk * 32);
            acc[c] = __builtin_amdgcn_mfma_f32_16x16x32_bf16(afr[kk], b, acc[c], 0, 0, 0);
        }
    }
    int orow0 = r0 + (lane >> 4) * 4;
    bool even = !(lane & 1);
#pragma unroll
    for (int c = 0; c < 8; c++) {
#pragma unroll
        for (int j = 0; j < 4; j++) {
            float v = acc[c][j];
            float pt = __shfl_xor(v, 1);
            if (even) {
                unsigned int u = (unsigned int)f2bf(v) | ((unsigned int)f2bf(pt) << 16);
                Cb[(size_t)(orow0 + j) * 64 + ((c * 16 + (lane & 15)) >> 1)] = u;
            }
        }
    }
}

// ---------------- conv2 aggregate: ballot-compact + bf16 rows + pool ---------
__global__ __launch_bounds__(256) void s2_pull(const unsigned short* __restrict__ csr16,
                                               const int* __restrict__ node_base,
                                               const int* __restrict__ deg,
                                               const int* __restrict__ perm,
                                               const int* __restrict__ new_id,
                                               const float* __restrict__ dinv2,
                                               const unsigned int* __restrict__ xwb2,
                                               const float* __restrict__ b2,
                                               float* __restrict__ pooled) {
    __shared__ float pr[HD];
    __shared__ int cnk[4][64];
    __shared__ float cds[4][64];
    int tid = threadIdx.x;
    if (tid < HD) pr[tid] = 0.f;
    __syncthreads();
    int b = blockIdx.x;              // 8192 blocks
    int xcd = b & 7, j = b >> 3;
    int g = (j >> 7) * 8 + xcd;
    int wv = tid >> 6;
    int m = g * KEEP + (j & 127) * 4 + wv;
    int lane = tid & 63;
    int node = perm[m];
    int gb = node & ~(NPERG - 1);
    int base = node_base[node], cnt = deg[node];
    int nk = 0; float ds = 0.f;
    if (lane < cnt) {
        int ns = new_id[gb + csr16[base + lane]];
        if (ns >= 0) { nk = ns; ds = dinv2[ns]; }
    }
    // ballot-compact survivors into per-wave LDS (ascending lane order)
    unsigned long long msk = __ballot(ds != 0.f);
    int pos = __popcll(msk & ((1ull << lane) - 1ull));
    if (ds != 0.f) { cnk[wv][pos] = nk; cds[wv][pos] = ds; }
    int na = __popcll(msk);
    float a0 = 0.f, a1 = 0.f;
    int k = 0;
    for (; k + 7 < na; k += 8) {
        int s0 = cnk[wv][k],     s1 = cnk[wv][k + 1];
        int s2 = cnk[wv][k + 2], s3 = cnk[wv][k + 3];
        int s4 = cnk[wv][k + 4], s5 = cnk[wv][k + 5];
        int s6 = cnk[wv][k + 6], s7 = cnk[wv][k + 7];
        float d0 = cds[wv][k],     d1 = cds[wv][k + 1];
        float d2 = cds[wv][k + 2], d3 = cds[wv][k + 3];
        float d4 = cds[wv][k + 4], d5 = cds[wv][k + 5];
        float d6 = cds[wv][k + 6], d7 = cds[wv][k + 7];
        unsigned int u0 = xwb2[(size_t)s0 * 64 + lane];
        unsigned int u1 = xwb2[(size_t)s1 * 64 + lane];
        unsigned int u2 = xwb2[(size_t)s2 * 64 + lane];
        unsigned int u3 = xwb2[(size_t)s3 * 64 + lane];
        unsigned int u4 = xwb2[(size_t)s4 * 64 + lane];
        unsigned int u5 = xwb2[(size_t)s5 * 64 + lane];
        unsigned int u6 = xwb2[(size_t)s6 * 64 + lane];
        unsigned int u7 = xwb2[(size_t)s7 * 64 + lane];
        a0 += d0 * __uint_as_float(u0 << 16); a1 += d0 * __uint_as_float(u0 & 0xFFFF0000u);
        a0 += d1 * __uint_as_float(u1 << 16); a1 += d1 * __uint_as_float(u1 & 0xFFFF0000u);
        a0 += d2 * __uint_as_float(u2 << 16); a1 += d2 * __uint_as_float(u2 & 0xFFFF0000u);
        a0 += d3 * __uint_as_float(u3 << 16); a1 += d3 * __uint_as_float(u3 & 0xFFFF0000u);
        a0 += d4 * __uint_as_float(u4 << 16); a1 += d4 * __uint_as_float(u4 & 0xFFFF0000u);
        a0 += d5 * __uint_as_float(u5 << 16); a1 += d5 * __uint_as_float(u5 & 0xFFFF0000u);
        a0 += d6 * __uint_as_float(u6 << 16); a1 += d6 * __uint_as_float(u6 & 0xFFFF0000u);
        a0 += d7 * __uint_as_float(u7 << 16); a1 += d7 * __uint_as_float(u7 & 0xFFFF0000u);
    }
    for (; k + 3 < na; k += 4) {
        int s0 = cnk[wv][k], s1 = cnk[wv][k + 1];
        int s2 = cnk[wv][k + 2], s3 = cnk[wv][k + 3];
        float d0 = cds[wv][k], d1 = cds[wv][k + 1];
        float d2 = cds[wv][k + 2], d3 = cds[wv][k + 3];
        unsigned int u0 = xwb2[(size_t)s0 * 64 + lane];
        unsigned int u1 = xwb2[(size_t)s1 * 64 + lane];
        unsigned int u2 = xwb2[(size_t)s2 * 64 + lane];
        unsigned int u3 = xwb2[(size_t)s3 * 64 + lane];
        a0 += d0 * __uint_as_float(u0 << 16); a1 += d0 * __uint_as_float(u0 & 0xFFFF0000u);
        a0 += d1 * __uint_as_float(u1 << 16); a1 += d1 * __uint_as_float(u1 & 0xFFFF0000u);
        a0 += d2 * __uint_as_float(u2 << 16); a1 += d2 * __uint_as_float(u2 & 0xFFFF0000u);
        a0 += d3 * __uint_as_float(u3 << 16); a1 += d3 * __uint_as_float(u3 & 0xFFFF0000u);
    }
    for (; k < na; k++) {
        int sk = cnk[wv][k];
        float dk = cds[wv][k];
        unsigned int u = xwb2[(size_t)sk * 64 + lane];
        a0 += dk * __uint_as_float(u << 16); a1 += dk * __uint_as_float(u & 0xFFFF0000u);
    }
    for (int kk = 64; kk < cnt; kk++) {    // deg>64 cold path
        int ns = new_id[gb + csr16[base + kk]];
        if (ns >= 0) {
            float dk = dinv2[ns];
            unsigned int u = xwb2[(size_t)ns * 64 + lane];
            a0 += dk * __uint_as_float(u << 16); a1 += dk * __uint_as_float(u & 0xFFFF0000u);
        }
    }
    float dn = dinv2[m];
    float self = dn * dn;
    unsigned int us = xwb2[(size_t)m * 64 + lane];
    float2 bb = ((const float2*)b2)[lane];
    float o0 = fmaxf(dn * a0 + self * __uint_as_float(us << 16) + bb.x, 0.f);
    float o1 = fmaxf(dn * a1 + self * __uint_as_float(us & 0xFFFF0000u) + bb.y, 0.f);
    atomicAdd(&pr[lane * 2], o0);
    atomicAdd(&pr[lane * 2 + 1], o1);
    __syncthreads();
    if (tid < HD) atomicAdd(&pooled[g * HD + tid], pr[tid]);
}

// ---------------- final linear: out = (pooled/512) @ Wl + bl -----------------
__global__ __launch_bounds__(128) void outk_kernel(const float* __restrict__ pooled,
                                                   const float* __restrict__ Wl,
                                                   const float* __restrict__ bl,
                                                   void* __restrict__ outv,
                                                   const int* __restrict__ flag) {
    int g = blockIdx.x, t = threadIdx.x;  // 128
    __shared__ float sp[HD];
    sp[t] = pooled[g * HD + t] * (1.0f / KEEP);
    __syncthreads();
    if (t < NC) {
        float acc = bl[t];
        for (int hh = 0; hh < HD; hh++) acc += sp[hh] * Wl[hh * NC + t];
        if (flag[0]) ((unsigned short*)outv)[g * NC + t] = f2bf(acc);
        else         ((float*)outv)[g * NC + t] = acc;
    }
}

extern "C" void kernel_launch(void* const* d_in, const int* in_sizes, int n_in,
                              void* d_out, int out_size, void* d_ws, size_t ws_size,
                              hipStream_t stream) {
    const int* ei   = (const int*)d_in[1];
    const int* srcv = ei;
    const int* dstv = ei + NEDGES;

    char* w = (char*)d_ws;
    const size_t MB = 1u << 20;
    const size_t KB = 1024;
    float* dinv1     = (float*)(w + 0);                 // 256 KB
    float* score     = (float*)(w + 256 * KB);          // 256 KB
    float* vals      = (float*)(w + 512 * KB);          // 128 KB
    int*   perm      = (int*)(w + 640 * KB);            // 128 KB
    int*   new_id    = (int*)(w + 768 * KB);            // 256 KB
    int*   deg1      = (int*)(w + 1024 * KB);           // 256 KB
    int*   node_base = (int*)(w + 1280 * KB);           // 256 KB
    float* dinv2     = (float*)(w + 1536 * KB);         // 128 KB
    float* invnorm   = (float*)(w + 1664 * KB);
    int*   flag      = (int*)(w + 1664 * KB + 64);
    int*   ghist     = (int*)(w + 1664 * KB + 1024);
    int*   gcur0     = (int*)(w + 1664 * KB + 2048);
    float* cw        = (float*)(w + 1700 * KB);         // 135 KB canonical weights
    float* pooled    = (float*)(w + 1840 * KB);         // 32 KB
    unsigned short* w1t = (unsigned short*)(w + 1880 * KB);  // 32 KB bf16 W1^T
    unsigned short* w2t = (unsigned short*)(w + 1912 * KB);  // 32 KB bf16 W2^T
    unsigned int* xw1b = (unsigned int*)(w + 2 * MB);   // [2,18) MB  bf16-packed xw1
    unsigned int* xw2b = (unsigned int*)(w + 18 * MB);  // [18,26) MB bf16-packed xw2
    unsigned int* hb = (unsigned int*)(w + 34 * MB);    // [34,50) MB bf16-packed h
    unsigned int* elist    = (unsigned int*)(w + 66 * MB);   // [66,71.25) MB fixed-stride
    unsigned short* csr16  = (unsigned short*)(w + 72 * MB); // [72,74.63) MB

    float* W1f = cw + OW1; float* W2f = cw + OW2; float* Wlf = cw + OWL;
    float* b1f = cw + OB1; float* b2f = cw + OB2; float* pf  = cw + OP;
    float* blf = cw + OBL;
    (void)W1f; (void)W2f;

    // zero ghist + gcur0 (binning in prep needs them zeroed; same-kernel init
    // would race). Covers [ghist, gcur0+64) = 1280 B.
    hipMemsetAsync(w + 1664 * KB + 1024, 0, 1280 + 256, stream);

    prep_kernel<<<648, 256, 0, stream>>>(d_in[3], d_in[4], d_in[5], d_in[6], d_in[7],
                                         d_in[8], d_in[9], flag, cw, invnorm, new_id,
                                         ghist, gcur0, pooled, w1t, w2t, srcv, dstv,
                                         elist);
    g1csr_kernel<<<NGRAPH + NNODES / 256, 1024, 0, stream>>>(
        elist, ghist, csr16, node_base, deg1, dinv1, d_in[0], w1t, xw1b, flag);
    s1_pull<<<NNODES / 4, 256, 0, stream>>>(csr16, node_base, deg1, dinv1, xw1b, b1f, pf,
                                            invnorm, hb, score);
    topk_kernel<<<NGRAPH, 1024, 0, stream>>>(score, vals, perm, new_id);
    g2deg_kernel<<<NGRAPH + M2 / 128, 512, 0, stream>>>(
        elist, ghist, new_id, dinv2, hb, perm, vals, w2t, xw2b);
    s2_pull<<<M2 / 4, 256, 0, stream>>>(csr16, node_base, deg1, perm, new_id, dinv2,
                                        xw2b, b2f, pooled);
    outk_kernel<<<NGRAPH, 128, 0, stream>>>(pooled, Wlf, blf, d_out, flag);

    (void)in_sizes; (void)n_in; (void)out_size; (void)ws_size;
}

// Round 11
// 234.331 us; speedup vs baseline: 1.3497x; 1.0406x over previous
//
#include <hip/hip_runtime.h>

#define NNODES 65536
#define NEDGES 1048576
#define NGRAPH 64
#define NPERG  1024
#define KEEP   512
#define M2     (NGRAPH * KEEP)   // 32768
#define HD     128
#define NC     10
#define EMAX   20480             // per-graph edge capacity (avg 16384, sigma~127)

// canonical weight block offsets (floats)
#define OW1 0
#define OW2 16384
#define OWL 32768
#define OB1 34048
#define OB2 34176
#define OP  34304
#define OBL 34432
#define NCVT 34448

typedef __attribute__((ext_vector_type(8))) short bf16x8;
typedef __attribute__((ext_vector_type(4))) float f32x4;

__device__ __forceinline__ float bf2f(unsigned short u) {
    return __uint_as_float(((unsigned int)u) << 16);
}
__device__ __forceinline__ unsigned short f2bf(float f) {
    unsigned int u = __float_as_uint(f);
    unsigned int r = (u + 0x7FFFu + ((u >> 16) & 1u)) >> 16;
    return (unsigned short)r;
}

// ------- prep: detect dtype + cvt weights + pnorm + init + edge binning ------
// Blocks [0,135): weight cvt; 135: pnorm; [136,392): init; [392,648): edge
// binning straight into fixed-stride per-graph elist regions (g*EMAX) via
// per-block LDS hist + one global reservation per graph (gcur0). Single pass
// over the edge list; ghist accumulated atomically. gcur0/ghist zeroed by a
// memsetAsync BEFORE this kernel (same-kernel init would race with binning).
__global__ __launch_bounds__(256) void prep_kernel(
    const void* __restrict__ W1, const void* __restrict__ b1, const void* __restrict__ p,
    const void* __restrict__ W2, const void* __restrict__ b2, const void* __restrict__ Wl,
    const void* __restrict__ bl, int* __restrict__ flag, float* __restrict__ cw,
    float* __restrict__ invnorm, int* __restrict__ new_id, int* __restrict__ ghist,
    int* __restrict__ gcur0, float* __restrict__ pooled,
    unsigned short* __restrict__ w1t, unsigned short* __restrict__ w2t,
    const int* __restrict__ src, const int* __restrict__ dst,
    unsigned int* __restrict__ elist) {
    int bid = blockIdx.x, t = threadIdx.x;
    const unsigned short* w1u = (const unsigned short*)W1;
    int local = 0;
    for (int i = t; i < 512; i += 256) {
        unsigned short u = w1u[2 * i];
        int e = (u >> 7) & 0xFF;
        local += (e >= 100 && e <= 140) ? 1 : 0;
    }
    __shared__ int red[256];
    __shared__ int lh[NGRAPH];
    __shared__ int lbase[NGRAPH];
    red[t] = local;
    __syncthreads();
    for (int off = 128; off; off >>= 1) {
        if (t < off) red[t] += red[t + off];
        __syncthreads();
    }
    int fl = (red[0] >= 384) ? 1 : 0;
    if (bid == 0 && t == 0) flag[0] = fl;

    if (bid < 135) {
        int gid = bid * 256 + t;
        if (gid < NCVT) {
            const void* srcp; int idx;
            if (gid < OB1) {
                if (gid < OW2)      { srcp = W1; idx = gid - OW1; }
                else if (gid < OWL) { srcp = W2; idx = gid - OW2; }
                else                { srcp = Wl; idx = gid - OWL; }
            } else {
                if (gid < OB2)      { srcp = b1; idx = gid - OB1; }
                else if (gid < OP)  { srcp = b2; idx = gid - OB2; }
                else if (gid < OBL) { srcp = p;  idx = gid - OP; }
                else                { srcp = bl; idx = gid - OBL; }
            }
            float v;
            if (gid >= OWL && gid < OB1 && idx >= 1280) v = 0.f;       // Wl pad
            else if (gid >= OBL && idx >= NC) v = 0.f;                  // bl pad
            else if (fl) v = bf2f(((const unsigned short*)srcp)[idx]);
            else v = ((const float*)srcp)[idx];
            cw[gid] = v;
            // bf16 transposed copies for the MFMA paths: w1t[n][k], w2t[n][k]
            if (gid < OW2) {
                int k = gid >> 7, n = gid & 127;
                w1t[n * 128 + k] = f2bf(v);
            } else if (gid < OWL) {
                int r = gid - OW2;
                int k = r >> 7, n = r & 127;
                w2t[n * 128 + k] = f2bf(v);
            }
        }
    } else if (bid == 135) {
        __shared__ float s2a[128];
        float pv = 0.f;
        if (t < 128) pv = fl ? bf2f(((const unsigned short*)p)[t]) : ((const float*)p)[t];
        if (t < 128) s2a[t] = pv * pv;
        __syncthreads();
        for (int off = 64; off; off >>= 1) {
            if (t < off) s2a[t] += s2a[t + off];
            __syncthreads();
        }
        if (t == 0) invnorm[0] = 1.0f / sqrtf(s2a[0]);
    } else if (bid < 392) {
        int i = (bid - 136) * 256 + t;
        new_id[i] = -1;
        if (i < NGRAPH * HD) pooled[i] = 0.f;
    } else {
        // ---- edge binning into fixed-stride regions ----
        if (t < NGRAPH) lh[t] = 0;
        __syncthreads();
        int e0 = (bid - 392) * 4096;  // 256 blocks x 4096 edges
        int gs[16]; unsigned int pk[16];
        for (int k = 0; k < 16; k++) {
            int e = e0 + k * 256 + t;
            int s = src[e], d = dst[e];
            gs[k] = s >> 10;
            pk[k] = (unsigned)(s & 1023) | ((unsigned)(d & 1023) << 10);
            atomicAdd(&lh[gs[k]], 1);
        }
        __syncthreads();
        if (t < NGRAPH) {
            int c = lh[t];
            lbase[t] = atomicAdd(&gcur0[t], c);
            atomicAdd(&ghist[t], c);
            lh[t] = 0;
        }
        __syncthreads();
        for (int k = 0; k < 16; k++) {
            int g = gs[k];
            int pos = lbase[g] + atomicAdd(&lh[g], 1);
            if (pos < EMAX) elist[g * EMAX + pos] = pk[k];
        }
    }
}

// ---------------- FUSED: per-graph CSR counting-sort (blocks 0..63) ----------
// ---------------- + GEMM1 xw1 = A @ W1 via MFMA (blocks 64..319) ------------
// Fixed-stride elist regions: base = g*EMAX, no prefix scan needed.
__global__ __launch_bounds__(1024) void g1csr_kernel(
    const unsigned int* __restrict__ elist, const int* __restrict__ ghist,
    unsigned short* __restrict__ csr16, int* __restrict__ node_base,
    int* __restrict__ deg_out, float* __restrict__ dinv_out,
    const void* __restrict__ Araw, const unsigned short* __restrict__ Wtb,
    unsigned int* __restrict__ Cb, const int* __restrict__ flag) {
    __shared__ unsigned short sc[EMAX];  // 40 KB (csr path only)
    __shared__ int cnt[NPERG];           // 4 KB
    __shared__ int cur[NPERG];           // 4 KB
    __shared__ int wsum[16];
    int bid = blockIdx.x, t = threadIdx.x;
    if (bid < NGRAPH) {
        int g = bid;
        cnt[t] = 0;
        __syncthreads();
        int base = g * EMAX;
        int n = ghist[g]; if (n > EMAX) n = EMAX;
        for (int j = t; j < n; j += 1024) atomicAdd(&cnt[(elist[base + j] >> 10) & 1023], 1);
        __syncthreads();
        int v = cnt[t];
        int lane = t & 63;
        int x = v;
        for (int off = 1; off < 64; off <<= 1) {
            int y = __shfl_up(x, off);
            if (lane >= off) x += y;
        }
        if (lane == 63) wsum[t >> 6] = x;
        __syncthreads();
        if (t < 16) {
            int wv = wsum[t];
            int wx = wv;
            for (int off = 1; off < 16; off <<= 1) {
                int y = __shfl_up(wx, off);
                if (t >= off) wx += y;
            }
            wsum[t] = wx - wv;  // exclusive wave base
        }
        __syncthreads();
        int excl = x - v + wsum[t >> 6];
        cur[t] = excl;
        deg_out[g * NPERG + t] = v;
        dinv_out[g * NPERG + t] = rsqrtf((float)v + 1.0f);
        node_base[g * NPERG + t] = base + excl;
        __syncthreads();
        for (int j = t; j < n; j += 1024) {
            unsigned int pk = elist[base + j];
            int d = (pk >> 10) & 1023;
            int pos = atomicAdd(&cur[d], 1);
            sc[pos] = (unsigned short)(pk & 1023);
        }
        __syncthreads();
        for (int j = t; j < n; j += 1024) csr16[base + j] = sc[j];
        return;
    }
    // ---- GEMM1 path: 16 waves/block, 16 rows/wave = 256 rows/block ----
    int row0 = (bid - NGRAPH) * 256;
    int wave = t >> 6, lane = t & 63;
    int r0 = row0 + wave * 16;
    int row = r0 + (lane & 15);
    int ko = (lane >> 4) * 8;                    // k offset within 32-chunk
    f32x4 acc[8];
#pragma unroll
    for (int c = 0; c < 8; c++) acc[c] = (f32x4){0.f, 0.f, 0.f, 0.f};
    bf16x8 afr[4];
    if (flag[0]) {
        const unsigned short* arow = (const unsigned short*)Araw + (size_t)row * HD + ko;
#pragma unroll
        for (int kk = 0; kk < 4; kk++) afr[kk] = *(const bf16x8*)(arow + kk * 32);
    } else {
        const float* arow = (const float*)Araw + (size_t)row * HD + ko;
#pragma unroll
        for (int kk = 0; kk < 4; kk++) {
            float4 f0 = *(const float4*)(arow + kk * 32);
            float4 f1 = *(const float4*)(arow + kk * 32 + 4);
            bf16x8 a;
            a[0] = (short)f2bf(f0.x); a[1] = (short)f2bf(f0.y);
            a[2] = (short)f2bf(f0.z); a[3] = (short)f2bf(f0.w);
            a[4] = (short)f2bf(f1.x); a[5] = (short)f2bf(f1.y);
            a[6] = (short)f2bf(f1.z); a[7] = (short)f2bf(f1.w);
            afr[kk] = a;
        }
    }
    const unsigned short* brow = Wtb + (lane & 15) * HD + ko;
#pragma unroll
    for (int kk = 0; kk < 4; kk++) {
#pragma unroll
        for (int c = 0; c < 8; c++) {
            bf16x8 b = *(const bf16x8*)(brow + c * 16 * HD + kk * 32);
            acc[c] = __builtin_amdgcn_mfma_f32_16x16x32_bf16(afr[kk], b, acc[c], 0, 0, 0);
        }
    }
    int orow0 = r0 + (lane >> 4) * 4;
    bool even = !(lane & 1);
#pragma unroll
    for (int c = 0; c < 8; c++) {
#pragma unroll
        for (int j = 0; j < 4; j++) {
            float v = acc[c][j];
            float pt = __shfl_xor(v, 1);
            if (even) {
                unsigned int u = (unsigned int)f2bf(v) | ((unsigned int)f2bf(pt) << 16);
                Cb[(size_t)(orow0 + j) * 64 + ((c * 16 + (lane & 15)) >> 1)] = u;
            }
        }
    }
}

// ---------------- conv1 aggregate (pull, 8-deep batched, bf16 rows) ----------
__global__ __launch_bounds__(256) void s1_pull(const unsigned short* __restrict__ csr16,
                                               const int* __restrict__ node_base,
                                               const int* __restrict__ deg,
                                               const float* __restrict__ dinv,
                                               const unsigned int* __restrict__ xwb,
                                               const float* __restrict__ b1,
                                               const float* __restrict__ pvec,
                                               const float* __restrict__ invnorm,
                                               unsigned int* __restrict__ hb,
                                               float* __restrict__ score) {
    int b = blockIdx.x;                 // 16384 blocks
    int xcd = b & 7, j = b >> 3;        // XCD-swizzle: graph pinned to one XCD
    int g = (j >> 8) * 8 + xcd;
    int n = g * NPERG + (j & 255) * 4 + (threadIdx.x >> 6);
    int lane = threadIdx.x & 63;
    int gb = g * NPERG;
    int base = node_base[n], cnt = deg[n];
    int e = 0; float ds = 0.f;
    if (lane < cnt) {
        e = csr16[base + lane];
        ds = dinv[gb + e];
    }
    float a0 = 0.f, a1 = 0.f;
    int klim = cnt < 64 ? cnt : 64;
    int k = 0;
    for (; k + 7 < klim; k += 8) {
        int s0 = __shfl(e, k),     s1 = __shfl(e, k + 1);
        int s2 = __shfl(e, k + 2), s3 = __shfl(e, k + 3);
        int s4 = __shfl(e, k + 4), s5 = __shfl(e, k + 5);
        int s6 = __shfl(e, k + 6), s7 = __shfl(e, k + 7);
        float d0 = __shfl(ds, k),     d1 = __shfl(ds, k + 1);
        float d2 = __shfl(ds, k + 2), d3 = __shfl(ds, k + 3);
        float d4 = __shfl(ds, k + 4), d5 = __shfl(ds, k + 5);
        float d6 = __shfl(ds, k + 6), d7 = __shfl(ds, k + 7);
        unsigned int u0 = xwb[(size_t)(gb + s0) * 64 + lane];
        unsigned int u1 = xwb[(size_t)(gb + s1) * 64 + lane];
        unsigned int u2 = xwb[(size_t)(gb + s2) * 64 + lane];
        unsigned int u3 = xwb[(size_t)(gb + s3) * 64 + lane];
        unsigned int u4 = xwb[(size_t)(gb + s4) * 64 + lane];
        unsigned int u5 = xwb[(size_t)(gb + s5) * 64 + lane];
        unsigned int u6 = xwb[(size_t)(gb + s6) * 64 + lane];
        unsigned int u7 = xwb[(size_t)(gb + s7) * 64 + lane];
        a0 += d0 * __uint_as_float(u0 << 16); a1 += d0 * __uint_as_float(u0 & 0xFFFF0000u);
        a0 += d1 * __uint_as_float(u1 << 16); a1 += d1 * __uint_as_float(u1 & 0xFFFF0000u);
        a0 += d2 * __uint_as_float(u2 << 16); a1 += d2 * __uint_as_float(u2 & 0xFFFF0000u);
        a0 += d3 * __uint_as_float(u3 << 16); a1 += d3 * __uint_as_float(u3 & 0xFFFF0000u);
        a0 += d4 * __uint_as_float(u4 << 16); a1 += d4 * __uint_as_float(u4 & 0xFFFF0000u);
        a0 += d5 * __uint_as_float(u5 << 16); a1 += d5 * __uint_as_float(u5 & 0xFFFF0000u);
        a0 += d6 * __uint_as_float(u6 << 16); a1 += d6 * __uint_as_float(u6 & 0xFFFF0000u);
        a0 += d7 * __uint_as_float(u7 << 16); a1 += d7 * __uint_as_float(u7 & 0xFFFF0000u);
    }
    for (; k + 3 < klim; k += 4) {
        int s0 = __shfl(e, k), s1 = __shfl(e, k + 1);
        int s2 = __shfl(e, k + 2), s3 = __shfl(e, k + 3);
        float d0 = __shfl(ds, k), d1 = __shfl(ds, k + 1);
        float d2 = __shfl(ds, k + 2), d3 = __shfl(ds, k + 3);
        unsigned int u0 = xwb[(size_t)(gb + s0) * 64 + lane];
        unsigned int u1 = xwb[(size_t)(gb + s1) * 64 + lane];
        unsigned int u2 = xwb[(size_t)(gb + s2) * 64 + lane];
        unsigned int u3 = xwb[(size_t)(gb + s3) * 64 + lane];
        a0 += d0 * __uint_as_float(u0 << 16); a1 += d0 * __uint_as_float(u0 & 0xFFFF0000u);
        a0 += d1 * __uint_as_float(u1 << 16); a1 += d1 * __uint_as_float(u1 & 0xFFFF0000u);
        a0 += d2 * __uint_as_float(u2 << 16); a1 += d2 * __uint_as_float(u2 & 0xFFFF0000u);
        a0 += d3 * __uint_as_float(u3 << 16); a1 += d3 * __uint_as_float(u3 & 0xFFFF0000u);
    }
    for (; k < klim; k++) {
        int sk = __shfl(e, k);
        float dk = __shfl(ds, k);
        unsigned int u = xwb[(size_t)(gb + sk) * 64 + lane];
        a0 += dk * __uint_as_float(u << 16); a1 += dk * __uint_as_float(u & 0xFFFF0000u);
    }
    for (; k < cnt; k++) {  // deg>64 cold path (P ~ 0, correctness only)
        int sk = csr16[base + k];
        float dk = dinv[gb + sk];
        unsigned int u = xwb[(size_t)(gb + sk) * 64 + lane];
        a0 += dk * __uint_as_float(u << 16); a1 += dk * __uint_as_float(u & 0xFFFF0000u);
    }
    float dn = dinv[n];
    float self = dn * dn;
    unsigned int us = xwb[(size_t)n * 64 + lane];
    float2 bb = ((const float2*)b1)[lane];
    float h0 = fmaxf(dn * a0 + self * __uint_as_float(us << 16) + bb.x, 0.f);
    float h1 = fmaxf(dn * a1 + self * __uint_as_float(us & 0xFFFF0000u) + bb.y, 0.f);
    hb[(size_t)n * 64 + lane] = (unsigned int)f2bf(h0) | ((unsigned int)f2bf(h1) << 16);
    float2 pp = ((const float2*)pvec)[lane];
    float sv = h0 * pp.x + h1 * pp.y;
    for (int off = 32; off; off >>= 1) sv += __shfl_down(sv, off);
    if (lane == 0) score[n] = tanhf(sv * invnorm[0]);
}

// ---------------- top-512 bitonic: register-resident, shuffle for j<64 -------
__global__ __launch_bounds__(1024) void topk_kernel(const float* __restrict__ score,
                                                    float* __restrict__ vals,
                                                    int* __restrict__ perm,
                                                    int* __restrict__ new_id) {
    __shared__ float sv[1024];
    __shared__ int si[1024];
    int g = blockIdx.x, t = threadIdx.x;
    float v = score[g * NPERG + t];
    int idx = t;
    for (int k = 2; k <= 1024; k <<= 1) {
        for (int j = k >> 1; j > 0; j >>= 1) {
            bool desc = ((t & k) == 0);
            bool up = (t & j) != 0;
            float vb; int ib;
            if (j >= 64) {
                sv[t] = v; si[t] = idx;
                __syncthreads();
                vb = sv[t ^ j]; ib = si[t ^ j];
                bool cmp = (v > vb) || (v == vb && idx < ib);  // lax.top_k tie rule
                bool keep = up ? (cmp != desc) : (cmp == desc);
                if (!keep) { v = vb; idx = ib; }
                __syncthreads();
            } else {
                vb = __shfl_xor(v, j);
                ib = __shfl_xor(idx, j);
                bool cmp = (v > vb) || (v == vb && idx < ib);
                bool keep = up ? (cmp != desc) : (cmp == desc);
                if (!keep) { v = vb; idx = ib; }
            }
        }
    }
    if (t < KEEP) {
        int node = g * NPERG + idx;
        int slot = g * KEEP + t;
        vals[slot] = v;
        perm[slot] = node;
        new_id[node] = slot;
    }
}

// ---------------- FUSED: deg2/dinv2 via CSR walk (blocks 0..63) --------------
// ---------------- + GEMM2 (vals*h[perm]) @ W2 MFMA, bf16-packed out ----------
// deg2[t] = #survivors in kept-node t's CSR neighbor list — identical multiset
// to the old per-edge count, but 524K lookups instead of 1M edges + 2M
// gathers + LDS atomics, and no third elist read.
__global__ __launch_bounds__(512) void g2deg_kernel(
    const unsigned short* __restrict__ csr16, const int* __restrict__ node_base,
    const int* __restrict__ deg,
    const int* __restrict__ new_id, float* __restrict__ dinv2,
    const unsigned int* __restrict__ hb, const int* __restrict__ perm,
    const float* __restrict__ vals, const unsigned short* __restrict__ Wtb,
    unsigned int* __restrict__ Cb) {
    int bid = blockIdx.x, t = threadIdx.x;
    if (bid < NGRAPH) {
        int g = bid;
        int kb = g * KEEP;
        int gb = g * NPERG;
        int node = perm[kb + t];            // 512 threads, one kept node each
        int base = node_base[node], cnt = deg[node];
        int c = 0;
        int j = 0;
        for (; j + 3 < cnt; j += 4) {
            int n0 = new_id[gb + csr16[base + j]];
            int n1 = new_id[gb + csr16[base + j + 1]];
            int n2 = new_id[gb + csr16[base + j + 2]];
            int n3 = new_id[gb + csr16[base + j + 3]];
            c += (n0 >= 0) + (n1 >= 0) + (n2 >= 0) + (n3 >= 0);
        }
        for (; j < cnt; j++) c += (new_id[gb + csr16[base + j]] >= 0) ? 1 : 0;
        dinv2[kb + t] = rsqrtf((float)c + 1.0f);
        return;
    }
    // ---- GEMM2 path: 8 waves/block, 16 rows/wave = 128 rows/block ----
    int row0 = (bid - NGRAPH) * 128;
    int wave = t >> 6, lane = t & 63;
    int r0 = row0 + wave * 16;
    int m = r0 + (lane & 15);
    int ko = (lane >> 4) * 8;
    float sc = vals[m];
    const unsigned int* arow = hb + (size_t)perm[m] * 64 + (ko >> 1);
    bf16x8 afr[4];
#pragma unroll
    for (int kk = 0; kk < 4; kk++) {
        uint4 q = *(const uint4*)(arow + kk * 16);
        bf16x8 a;
        a[0] = (short)f2bf(bf2f((unsigned short)q.x) * sc);
        a[1] = (short)f2bf(bf2f((unsigned short)(q.x >> 16)) * sc);
        a[2] = (short)f2bf(bf2f((unsigned short)q.y) * sc);
        a[3] = (short)f2bf(bf2f((unsigned short)(q.y >> 16)) * sc);
        a[4] = (short)f2bf(bf2f((unsigned short)q.z) * sc);
        a[5] = (short)f2bf(bf2f((unsigned short)(q.z >> 16)) * sc);
        a[6] = (short)f2bf(bf2f((unsigned short)q.w) * sc);
        a[7] = (short)f2bf(bf2f((unsigned short)(q.w >> 16)) * sc);
        afr[kk] = a;
    }
    f32x4 acc[8];
#pragma unroll
    for (int c = 0; c < 8; c++) acc[c] = (f32x4){0.f, 0.f, 0.f, 0.f};
    const unsigned short* brow = Wtb + (lane & 15) * HD + ko;
#pragma unroll
    for (int kk = 0; kk < 4; kk++) {
#pragma unroll
        for (int c = 0; c < 8; c++) {
            bf16x8 b = *(const bf16x8*)(brow + c * 16 * HD + kk * 32);
            acc[c] = __builtin_amdgcn_mfma_f32_16x16x32_bf16(afr[kk], b, acc[c], 0, 0, 0);
        }
    }
    int orow0 = r0 + (lane >> 4) * 4;
    bool even = !(lane & 1);
#pragma unroll
    for (int c = 0; c < 8; c++) {
#pragma unroll
        for (int j = 0; j < 4; j++) {
            float v = acc[c][j];
            float pt = __shfl_xor(v, 1);
            if (even) {
                unsigned int u = (unsigned int)f2bf(v) | ((unsigned int)f2bf(pt) << 16);
                Cb[(size_t)(orow0 + j) * 64 + ((c * 16 + (lane & 15)) >> 1)] = u;
            }
        }
    }
}

// ---------------- conv2 aggregate: ballot-compact + bf16 rows + pool ---------
__global__ __launch_bounds__(256) void s2_pull(const unsigned short* __restrict__ csr16,
                                               const int* __restrict__ node_base,
                                               const int* __restrict__ deg,
                                               const int* __restrict__ perm,
                                               const int* __restrict__ new_id,
                                               const float* __restrict__ dinv2,
                                               const unsigned int* __restrict__ xwb2,
                                               const float* __restrict__ b2,
                                               float* __restrict__ pooled) {
    __shared__ float pr[HD];
    __shared__ int cnk[4][64];
    __shared__ float cds[4][64];
    int tid = threadIdx.x;
    if (tid < HD) pr[tid] = 0.f;
    __syncthreads();
    int b = blockIdx.x;              // 8192 blocks
    int xcd = b & 7, j = b >> 3;
    int g = (j >> 7) * 8 + xcd;
    int wv = tid >> 6;
    int m = g * KEEP + (j & 127) * 4 + wv;
    int lane = tid & 63;
    int node = perm[m];
    int gb = node & ~(NPERG - 1);
    int base = node_base[node], cnt = deg[node];
    int nk = 0; float ds = 0.f;
    if (lane < cnt) {
        int ns = new_id[gb + csr16[base + lane]];
        if (ns >= 0) { nk = ns; ds = dinv2[ns]; }
    }
    // ballot-compact survivors into per-wave LDS (ascending lane order)
    unsigned long long msk = __ballot(ds != 0.f);
    int pos = __popcll(msk & ((1ull << lane) - 1ull));
    if (ds != 0.f) { cnk[wv][pos] = nk; cds[wv][pos] = ds; }
    int na = __popcll(msk);
    float a0 = 0.f, a1 = 0.f;
    int k = 0;
    for (; k + 7 < na; k += 8) {
        int s0 = cnk[wv][k],     s1 = cnk[wv][k + 1];
        int s2 = cnk[wv][k + 2], s3 = cnk[wv][k + 3];
        int s4 = cnk[wv][k + 4], s5 = cnk[wv][k + 5];
        int s6 = cnk[wv][k + 6], s7 = cnk[wv][k + 7];
        float d0 = cds[wv][k],     d1 = cds[wv][k + 1];
        float d2 = cds[wv][k + 2], d3 = cds[wv][k + 3];
        float d4 = cds[wv][k + 4], d5 = cds[wv][k + 5];
        float d6 = cds[wv][k + 6], d7 = cds[wv][k + 7];
        unsigned int u0 = xwb2[(size_t)s0 * 64 + lane];
        unsigned int u1 = xwb2[(size_t)s1 * 64 + lane];
        unsigned int u2 = xwb2[(size_t)s2 * 64 + lane];
        unsigned int u3 = xwb2[(size_t)s3 * 64 + lane];
        unsigned int u4 = xwb2[(size_t)s4 * 64 + lane];
        unsigned int u5 = xwb2[(size_t)s5 * 64 + lane];
        unsigned int u6 = xwb2[(size_t)s6 * 64 + lane];
        unsigned int u7 = xwb2[(size_t)s7 * 64 + lane];
        a0 += d0 * __uint_as_float(u0 << 16); a1 += d0 * __uint_as_float(u0 & 0xFFFF0000u);
        a0 += d1 * __uint_as_float(u1 << 16); a1 += d1 * __uint_as_float(u1 & 0xFFFF0000u);
        a0 += d2 * __uint_as_float(u2 << 16); a1 += d2 * __uint_as_float(u2 & 0xFFFF0000u);
        a0 += d3 * __uint_as_float(u3 << 16); a1 += d3 * __uint_as_float(u3 & 0xFFFF0000u);
        a0 += d4 * __uint_as_float(u4 << 16); a1 += d4 * __uint_as_float(u4 & 0xFFFF0000u);
        a0 += d5 * __uint_as_float(u5 << 16); a1 += d5 * __uint_as_float(u5 & 0xFFFF0000u);
        a0 += d6 * __uint_as_float(u6 << 16); a1 += d6 * __uint_as_float(u6 & 0xFFFF0000u);
        a0 += d7 * __uint_as_float(u7 << 16); a1 += d7 * __uint_as_float(u7 & 0xFFFF0000u);
    }
    for (; k + 3 < na; k += 4) {
        int s0 = cnk[wv][k], s1 = cnk[wv][k + 1];
        int s2 = cnk[wv][k + 2], s3 = cnk[wv][k + 3];
        float d0 = cds[wv][k], d1 = cds[wv][k + 1];
        float d2 = cds[wv][k + 2], d3 = cds[wv][k + 3];
        unsigned int u0 = xwb2[(size_t)s0 * 64 + lane];
        unsigned int u1 = xwb2[(size_t)s1 * 64 + lane];
        unsigned int u2 = xwb2[(size_t)s2 * 64 + lane];
        unsigned int u3 = xwb2[(size_t)s3 * 64 + lane];
        a0 += d0 * __uint_as_float(u0 << 16); a1 += d0 * __uint_as_float(u0 & 0xFFFF0000u);
        a0 += d1 * __uint_as_float(u1 << 16); a1 += d1 * __uint_as_float(u1 & 0xFFFF0000u);
        a0 += d2 * __uint_as_float(u2 << 16); a1 += d2 * __uint_as_float(u2 & 0xFFFF0000u);
        a0 += d3 * __uint_as_float(u3 << 16); a1 += d3 * __uint_as_float(u3 & 0xFFFF0000u);
    }
    for (; k < na; k++) {
        int sk = cnk[wv][k];
        float dk = cds[wv][k];
        unsigned int u = xwb2[(size_t)sk * 64 + lane];
        a0 += dk * __uint_as_float(u << 16); a1 += dk * __uint_as_float(u & 0xFFFF0000u);
    }
    for (int kk = 64; kk < cnt; kk++) {    // deg>64 cold path
        int ns = new_id[gb + csr16[base + kk]];
        if (ns >= 0) {
            float dk = dinv2[ns];
            unsigned int u = xwb2[(size_t)ns * 64 + lane];
            a0 += dk * __uint_as_float(u << 16); a1 += dk * __uint_as_float(u & 0xFFFF0000u);
        }
    }
    float dn = dinv2[m];
    float self = dn * dn;
    unsigned int us = xwb2[(size_t)m * 64 + lane];
    float2 bb = ((const float2*)b2)[lane];
    float o0 = fmaxf(dn * a0 + self * __uint_as_float(us << 16) + bb.x, 0.f);
    float o1 = fmaxf(dn * a1 + self * __uint_as_float(us & 0xFFFF0000u) + bb.y, 0.f);
    atomicAdd(&pr[lane * 2], o0);
    atomicAdd(&pr[lane * 2 + 1], o1);
    __syncthreads();
    if (tid < HD) atomicAdd(&pooled[g * HD + tid], pr[tid]);
}

// ---------------- final linear: out = (pooled/512) @ Wl + bl -----------------
__global__ __launch_bounds__(128) void outk_kernel(const float* __restrict__ pooled,
                                                   const float* __restrict__ Wl,
                                                   const float* __restrict__ bl,
                                                   void* __restrict__ outv,
                                                   const int* __restrict__ flag) {
    int g = blockIdx.x, t = threadIdx.x;  // 128
    __shared__ float sp[HD];
    sp[t] = pooled[g * HD + t] * (1.0f / KEEP);
    __syncthreads();
    if (t < NC) {
        float acc = bl[t];
        for (int hh = 0; hh < HD; hh++) acc += sp[hh] * Wl[hh * NC + t];
        if (flag[0]) ((unsigned short*)outv)[g * NC + t] = f2bf(acc);
        else         ((float*)outv)[g * NC + t] = acc;
    }
}

extern "C" void kernel_launch(void* const* d_in, const int* in_sizes, int n_in,
                              void* d_out, int out_size, void* d_ws, size_t ws_size,
                              hipStream_t stream) {
    const int* ei   = (const int*)d_in[1];
    const int* srcv = ei;
    const int* dstv = ei + NEDGES;

    char* w = (char*)d_ws;
    const size_t MB = 1u << 20;
    const size_t KB = 1024;
    float* dinv1     = (float*)(w + 0);                 // 256 KB
    float* score     = (float*)(w + 256 * KB);          // 256 KB
    float* vals      = (float*)(w + 512 * KB);          // 128 KB
    int*   perm      = (int*)(w + 640 * KB);            // 128 KB
    int*   new_id    = (int*)(w + 768 * KB);            // 256 KB
    int*   deg1      = (int*)(w + 1024 * KB);           // 256 KB
    int*   node_base = (int*)(w + 1280 * KB);           // 256 KB
    float* dinv2     = (float*)(w + 1536 * KB);         // 128 KB
    float* invnorm   = (float*)(w + 1664 * KB);
    int*   flag      = (int*)(w + 1664 * KB + 64);
    int*   ghist     = (int*)(w + 1664 * KB + 1024);
    int*   gcur0     = (int*)(w + 1664 * KB + 2048);
    float* cw        = (float*)(w + 1700 * KB);         // 135 KB canonical weights
    float* pooled    = (float*)(w + 1840 * KB);         // 32 KB
    unsigned short* w1t = (unsigned short*)(w + 1880 * KB);  // 32 KB bf16 W1^T
    unsigned short* w2t = (unsigned short*)(w + 1912 * KB);  // 32 KB bf16 W2^T
    unsigned int* xw1b = (unsigned int*)(w + 2 * MB);   // [2,18) MB  bf16-packed xw1
    unsigned int* xw2b = (unsigned int*)(w + 18 * MB);  // [18,26) MB bf16-packed xw2
    unsigned int* hb = (unsigned int*)(w + 34 * MB);    // [34,50) MB bf16-packed h
    unsigned int* elist    = (unsigned int*)(w + 66 * MB);   // [66,71.25) MB fixed-stride
    unsigned short* csr16  = (unsigned short*)(w + 72 * MB); // [72,74.63) MB

    float* W1f = cw + OW1; float* W2f = cw + OW2; float* Wlf = cw + OWL;
    float* b1f = cw + OB1; float* b2f = cw + OB2; float* pf  = cw + OP;
    float* blf = cw + OBL;
    (void)W1f; (void)W2f;

    // zero ghist + gcur0 (binning in prep needs them zeroed; same-kernel init
    // would race). Covers [ghist, gcur0+64) = 1280 B.
    hipMemsetAsync(w + 1664 * KB + 1024, 0, 1280 + 256, stream);

    prep_kernel<<<648, 256, 0, stream>>>(d_in[3], d_in[4], d_in[5], d_in[6], d_in[7],
                                         d_in[8], d_in[9], flag, cw, invnorm, new_id,
                                         ghist, gcur0, pooled, w1t, w2t, srcv, dstv,
                                         elist);
    g1csr_kernel<<<NGRAPH + NNODES / 256, 1024, 0, stream>>>(
        elist, ghist, csr16, node_base, deg1, dinv1, d_in[0], w1t, xw1b, flag);
    s1_pull<<<NNODES / 4, 256, 0, stream>>>(csr16, node_base, deg1, dinv1, xw1b, b1f, pf,
                                            invnorm, hb, score);
    topk_kernel<<<NGRAPH, 1024, 0, stream>>>(score, vals, perm, new_id);
    g2deg_kernel<<<NGRAPH + M2 / 128, 512, 0, stream>>>(
        csr16, node_base, deg1, new_id, dinv2, hb, perm, vals, w2t, xw2b);
    s2_pull<<<M2 / 4, 256, 0, stream>>>(csr16, node_base, deg1, perm, new_id, dinv2,
                                        xw2b, b2f, pooled);
    outk_kernel<<<NGRAPH, 128, 0, stream>>>(pooled, Wlf, blf, d_out, flag);

    (void)in_sizes; (void)n_in; (void)out_size; (void)ws_size;
}

// Round 12
// 216.073 us; speedup vs baseline: 1.4638x; 1.0845x over previous
//
#include <hip/hip_runtime.h>

#define NNODES 65536
#define NEDGES 1048576
#define NGRAPH 64
#define NPERG  1024
#define KEEP   512
#define M2     (NGRAPH * KEEP)   // 32768
#define HD     128
#define NC     10
#define EMAX   20480             // per-graph edge capacity (avg 16384, sigma~127)

// canonical weight block offsets (floats)
#define OW1 0
#define OW2 16384
#define OWL 32768
#define OB1 34048
#define OB2 34176
#define OP  34304
#define OBL 34432
#define NCVT 34448

typedef __attribute__((ext_vector_type(8))) short bf16x8;
typedef __attribute__((ext_vector_type(4))) float f32x4;

__device__ __forceinline__ float bf2f(unsigned short u) {
    return __uint_as_float(((unsigned int)u) << 16);
}
__device__ __forceinline__ unsigned short f2bf(float f) {
    unsigned int u = __float_as_uint(f);
    unsigned int r = (u + 0x7FFFu + ((u >> 16) & 1u)) >> 16;
    return (unsigned short)r;
}

// ------- prep: detect dtype + cvt weights + pnorm + init + edge binning ------
__global__ __launch_bounds__(256) void prep_kernel(
    const void* __restrict__ W1, const void* __restrict__ b1, const void* __restrict__ p,
    const void* __restrict__ W2, const void* __restrict__ b2, const void* __restrict__ Wl,
    const void* __restrict__ bl, int* __restrict__ flag, float* __restrict__ cw,
    float* __restrict__ invnorm, int* __restrict__ new_id, int* __restrict__ ghist,
    int* __restrict__ gcur0, float* __restrict__ pooled,
    unsigned short* __restrict__ w1t, unsigned short* __restrict__ w2t,
    const int* __restrict__ src, const int* __restrict__ dst,
    unsigned int* __restrict__ elist) {
    int bid = blockIdx.x, t = threadIdx.x;
    const unsigned short* w1u = (const unsigned short*)W1;
    int local = 0;
    for (int i = t; i < 512; i += 256) {
        unsigned short u = w1u[2 * i];
        int e = (u >> 7) & 0xFF;
        local += (e >= 100 && e <= 140) ? 1 : 0;
    }
    __shared__ int red[256];
    __shared__ int lh[NGRAPH];
    __shared__ int lbase[NGRAPH];
    red[t] = local;
    __syncthreads();
    for (int off = 128; off; off >>= 1) {
        if (t < off) red[t] += red[t + off];
        __syncthreads();
    }
    int fl = (red[0] >= 384) ? 1 : 0;
    if (bid == 0 && t == 0) flag[0] = fl;

    if (bid < 135) {
        int gid = bid * 256 + t;
        if (gid < NCVT) {
            const void* srcp; int idx;
            if (gid < OB1) {
                if (gid < OW2)      { srcp = W1; idx = gid - OW1; }
                else if (gid < OWL) { srcp = W2; idx = gid - OW2; }
                else                { srcp = Wl; idx = gid - OWL; }
            } else {
                if (gid < OB2)      { srcp = b1; idx = gid - OB1; }
                else if (gid < OP)  { srcp = b2; idx = gid - OB2; }
                else if (gid < OBL) { srcp = p;  idx = gid - OP; }
                else                { srcp = bl; idx = gid - OBL; }
            }
            float v;
            if (gid >= OWL && gid < OB1 && idx >= 1280) v = 0.f;       // Wl pad
            else if (gid >= OBL && idx >= NC) v = 0.f;                  // bl pad
            else if (fl) v = bf2f(((const unsigned short*)srcp)[idx]);
            else v = ((const float*)srcp)[idx];
            cw[gid] = v;
            // bf16 transposed copies for the MFMA paths: w1t[n][k], w2t[n][k]
            if (gid < OW2) {
                int k = gid >> 7, n = gid & 127;
                w1t[n * 128 + k] = f2bf(v);
            } else if (gid < OWL) {
                int r = gid - OW2;
                int k = r >> 7, n = r & 127;
                w2t[n * 128 + k] = f2bf(v);
            }
        }
    } else if (bid == 135) {
        __shared__ float s2a[128];
        float pv = 0.f;
        if (t < 128) pv = fl ? bf2f(((const unsigned short*)p)[t]) : ((const float*)p)[t];
        if (t < 128) s2a[t] = pv * pv;
        __syncthreads();
        for (int off = 64; off; off >>= 1) {
            if (t < off) s2a[t] += s2a[t + off];
            __syncthreads();
        }
        if (t == 0) invnorm[0] = 1.0f / sqrtf(s2a[0]);
    } else if (bid < 392) {
        int i = (bid - 136) * 256 + t;
        new_id[i] = -1;
        if (i < NGRAPH * HD) pooled[i] = 0.f;
    } else {
        // ---- edge binning into fixed-stride regions ----
        if (t < NGRAPH) lh[t] = 0;
        __syncthreads();
        int e0 = (bid - 392) * 4096;  // 256 blocks x 4096 edges
        int gs[16]; unsigned int pk[16];
        for (int k = 0; k < 16; k++) {
            int e = e0 + k * 256 + t;
            int s = src[e], d = dst[e];
            gs[k] = s >> 10;
            pk[k] = (unsigned)(s & 1023) | ((unsigned)(d & 1023) << 10);
            atomicAdd(&lh[gs[k]], 1);
        }
        __syncthreads();
        if (t < NGRAPH) {
            int c = lh[t];
            lbase[t] = atomicAdd(&gcur0[t], c);
            atomicAdd(&ghist[t], c);
            lh[t] = 0;
        }
        __syncthreads();
        for (int k = 0; k < 16; k++) {
            int g = gs[k];
            int pos = lbase[g] + atomicAdd(&lh[g], 1);
            if (pos < EMAX) elist[g * EMAX + pos] = pk[k];
        }
    }
}

// ---------------- FUSED: per-graph CSR counting-sort (blocks 0..63) ----------
// ---------------- + GEMM1 xw1 = A @ W1 via MFMA (blocks 64..319) ------------
__global__ __launch_bounds__(1024) void g1csr_kernel(
    const unsigned int* __restrict__ elist, const int* __restrict__ ghist,
    unsigned short* __restrict__ csr16, int* __restrict__ node_base,
    int* __restrict__ deg_out, float* __restrict__ dinv_out,
    const void* __restrict__ Araw, const unsigned short* __restrict__ Wtb,
    unsigned int* __restrict__ Cb, const int* __restrict__ flag) {
    __shared__ unsigned short sc[EMAX];  // 40 KB (csr path only)
    __shared__ int cnt[NPERG];           // 4 KB
    __shared__ int cur[NPERG];           // 4 KB
    __shared__ int wsum[16];
    int bid = blockIdx.x, t = threadIdx.x;
    if (bid < NGRAPH) {
        int g = bid;
        cnt[t] = 0;
        __syncthreads();
        int base = g * EMAX;
        int n = ghist[g]; if (n > EMAX) n = EMAX;
        for (int j = t; j < n; j += 1024) atomicAdd(&cnt[(elist[base + j] >> 10) & 1023], 1);
        __syncthreads();
        int v = cnt[t];
        int lane = t & 63;
        int x = v;
        for (int off = 1; off < 64; off <<= 1) {
            int y = __shfl_up(x, off);
            if (lane >= off) x += y;
        }
        if (lane == 63) wsum[t >> 6] = x;
        __syncthreads();
        if (t < 16) {
            int wv = wsum[t];
            int wx = wv;
            for (int off = 1; off < 16; off <<= 1) {
                int y = __shfl_up(wx, off);
                if (t >= off) wx += y;
            }
            wsum[t] = wx - wv;  // exclusive wave base
        }
        __syncthreads();
        int excl = x - v + wsum[t >> 6];
        cur[t] = excl;
        deg_out[g * NPERG + t] = v;
        dinv_out[g * NPERG + t] = rsqrtf((float)v + 1.0f);
        node_base[g * NPERG + t] = base + excl;
        __syncthreads();
        for (int j = t; j < n; j += 1024) {
            unsigned int pk = elist[base + j];
            int d = (pk >> 10) & 1023;
            int pos = atomicAdd(&cur[d], 1);
            sc[pos] = (unsigned short)(pk & 1023);
        }
        __syncthreads();
        for (int j = t; j < n; j += 1024) csr16[base + j] = sc[j];
        return;
    }
    // ---- GEMM1 path: 16 waves/block, 16 rows/wave = 256 rows/block ----
    int row0 = (bid - NGRAPH) * 256;
    int wave = t >> 6, lane = t & 63;
    int r0 = row0 + wave * 16;
    int row = r0 + (lane & 15);
    int ko = (lane >> 4) * 8;                    // k offset within 32-chunk
    f32x4 acc[8];
#pragma unroll
    for (int c = 0; c < 8; c++) acc[c] = (f32x4){0.f, 0.f, 0.f, 0.f};
    bf16x8 afr[4];
    if (flag[0]) {
        const unsigned short* arow = (const unsigned short*)Araw + (size_t)row * HD + ko;
#pragma unroll
        for (int kk = 0; kk < 4; kk++) afr[kk] = *(const bf16x8*)(arow + kk * 32);
    } else {
        const float* arow = (const float*)Araw + (size_t)row * HD + ko;
#pragma unroll
        for (int kk = 0; kk < 4; kk++) {
            float4 f0 = *(const float4*)(arow + kk * 32);
            float4 f1 = *(const float4*)(arow + kk * 32 + 4);
            bf16x8 a;
            a[0] = (short)f2bf(f0.x); a[1] = (short)f2bf(f0.y);
            a[2] = (short)f2bf(f0.z); a[3] = (short)f2bf(f0.w);
            a[4] = (short)f2bf(f1.x); a[5] = (short)f2bf(f1.y);
            a[6] = (short)f2bf(f1.z); a[7] = (short)f2bf(f1.w);
            afr[kk] = a;
        }
    }
    const unsigned short* brow = Wtb + (lane & 15) * HD + ko;
#pragma unroll
    for (int kk = 0; kk < 4; kk++) {
#pragma unroll
        for (int c = 0; c < 8; c++) {
            bf16x8 b = *(const bf16x8*)(brow + c * 16 * HD + kk * 32);
            acc[c] = __builtin_amdgcn_mfma_f32_16x16x32_bf16(afr[kk], b, acc[c], 0, 0, 0);
        }
    }
    int orow0 = r0 + (lane >> 4) * 4;
    bool even = !(lane & 1);
#pragma unroll
    for (int c = 0; c < 8; c++) {
#pragma unroll
        for (int j = 0; j < 4; j++) {
            float v = acc[c][j];
            float pt = __shfl_xor(v, 1);
            if (even) {
                unsigned int u = (unsigned int)f2bf(v) | ((unsigned int)f2bf(pt) << 16);
                Cb[(size_t)(orow0 + j) * 64 + ((c * 16 + (lane & 15)) >> 1)] = u;
            }
        }
    }
}

// ---------------- conv1 aggregate (pull, 8-deep batched, bf16 rows) ----------
__global__ __launch_bounds__(256) void s1_pull(const unsigned short* __restrict__ csr16,
                                               const int* __restrict__ node_base,
                                               const int* __restrict__ deg,
                                               const float* __restrict__ dinv,
                                               const unsigned int* __restrict__ xwb,
                                               const float* __restrict__ b1,
                                               const float* __restrict__ pvec,
                                               const float* __restrict__ invnorm,
                                               unsigned int* __restrict__ hb,
                                               float* __restrict__ score) {
    int b = blockIdx.x;                 // 16384 blocks
    int xcd = b & 7, j = b >> 3;        // XCD-swizzle: graph pinned to one XCD
    int g = (j >> 8) * 8 + xcd;
    int n = g * NPERG + (j & 255) * 4 + (threadIdx.x >> 6);
    int lane = threadIdx.x & 63;
    int gb = g * NPERG;
    int base = node_base[n], cnt = deg[n];
    int e = 0; float ds = 0.f;
    if (lane < cnt) {
        e = csr16[base + lane];
        ds = dinv[gb + e];
    }
    float a0 = 0.f, a1 = 0.f;
    int klim = cnt < 64 ? cnt : 64;
    int k = 0;
    for (; k + 7 < klim; k += 8) {
        int s0 = __shfl(e, k),     s1 = __shfl(e, k + 1);
        int s2 = __shfl(e, k + 2), s3 = __shfl(e, k + 3);
        int s4 = __shfl(e, k + 4), s5 = __shfl(e, k + 5);
        int s6 = __shfl(e, k + 6), s7 = __shfl(e, k + 7);
        float d0 = __shfl(ds, k),     d1 = __shfl(ds, k + 1);
        float d2 = __shfl(ds, k + 2), d3 = __shfl(ds, k + 3);
        float d4 = __shfl(ds, k + 4), d5 = __shfl(ds, k + 5);
        float d6 = __shfl(ds, k + 6), d7 = __shfl(ds, k + 7);
        unsigned int u0 = xwb[(size_t)(gb + s0) * 64 + lane];
        unsigned int u1 = xwb[(size_t)(gb + s1) * 64 + lane];
        unsigned int u2 = xwb[(size_t)(gb + s2) * 64 + lane];
        unsigned int u3 = xwb[(size_t)(gb + s3) * 64 + lane];
        unsigned int u4 = xwb[(size_t)(gb + s4) * 64 + lane];
        unsigned int u5 = xwb[(size_t)(gb + s5) * 64 + lane];
        unsigned int u6 = xwb[(size_t)(gb + s6) * 64 + lane];
        unsigned int u7 = xwb[(size_t)(gb + s7) * 64 + lane];
        a0 += d0 * __uint_as_float(u0 << 16); a1 += d0 * __uint_as_float(u0 & 0xFFFF0000u);
        a0 += d1 * __uint_as_float(u1 << 16); a1 += d1 * __uint_as_float(u1 & 0xFFFF0000u);
        a0 += d2 * __uint_as_float(u2 << 16); a1 += d2 * __uint_as_float(u2 & 0xFFFF0000u);
        a0 += d3 * __uint_as_float(u3 << 16); a1 += d3 * __uint_as_float(u3 & 0xFFFF0000u);
        a0 += d4 * __uint_as_float(u4 << 16); a1 += d4 * __uint_as_float(u4 & 0xFFFF0000u);
        a0 += d5 * __uint_as_float(u5 << 16); a1 += d5 * __uint_as_float(u5 & 0xFFFF0000u);
        a0 += d6 * __uint_as_float(u6 << 16); a1 += d6 * __uint_as_float(u6 & 0xFFFF0000u);
        a0 += d7 * __uint_as_float(u7 << 16); a1 += d7 * __uint_as_float(u7 & 0xFFFF0000u);
    }
    for (; k + 3 < klim; k += 4) {
        int s0 = __shfl(e, k), s1 = __shfl(e, k + 1);
        int s2 = __shfl(e, k + 2), s3 = __shfl(e, k + 3);
        float d0 = __shfl(ds, k), d1 = __shfl(ds, k + 1);
        float d2 = __shfl(ds, k + 2), d3 = __shfl(ds, k + 3);
        unsigned int u0 = xwb[(size_t)(gb + s0) * 64 + lane];
        unsigned int u1 = xwb[(size_t)(gb + s1) * 64 + lane];
        unsigned int u2 = xwb[(size_t)(gb + s2) * 64 + lane];
        unsigned int u3 = xwb[(size_t)(gb + s3) * 64 + lane];
        a0 += d0 * __uint_as_float(u0 << 16); a1 += d0 * __uint_as_float(u0 & 0xFFFF0000u);
        a0 += d1 * __uint_as_float(u1 << 16); a1 += d1 * __uint_as_float(u1 & 0xFFFF0000u);
        a0 += d2 * __uint_as_float(u2 << 16); a1 += d2 * __uint_as_float(u2 & 0xFFFF0000u);
        a0 += d3 * __uint_as_float(u3 << 16); a1 += d3 * __uint_as_float(u3 & 0xFFFF0000u);
    }
    for (; k < klim; k++) {
        int sk = __shfl(e, k);
        float dk = __shfl(ds, k);
        unsigned int u = xwb[(size_t)(gb + sk) * 64 + lane];
        a0 += dk * __uint_as_float(u << 16); a1 += dk * __uint_as_float(u & 0xFFFF0000u);
    }
    for (; k < cnt; k++) {  // deg>64 cold path (P ~ 0, correctness only)
        int sk = csr16[base + k];
        float dk = dinv[gb + sk];
        unsigned int u = xwb[(size_t)(gb + sk) * 64 + lane];
        a0 += dk * __uint_as_float(u << 16); a1 += dk * __uint_as_float(u & 0xFFFF0000u);
    }
    float dn = dinv[n];
    float self = dn * dn;
    unsigned int us = xwb[(size_t)n * 64 + lane];
    float2 bb = ((const float2*)b1)[lane];
    float h0 = fmaxf(dn * a0 + self * __uint_as_float(us << 16) + bb.x, 0.f);
    float h1 = fmaxf(dn * a1 + self * __uint_as_float(us & 0xFFFF0000u) + bb.y, 0.f);
    hb[(size_t)n * 64 + lane] = (unsigned int)f2bf(h0) | ((unsigned int)f2bf(h1) << 16);
    float2 pp = ((const float2*)pvec)[lane];
    float sv = h0 * pp.x + h1 * pp.y;
    for (int off = 32; off; off >>= 1) sv += __shfl_down(sv, off);
    if (lane == 0) score[n] = tanhf(sv * invnorm[0]);
}

// ---------------- top-512 bitonic: register-resident, shuffle for j<64 -------
__global__ __launch_bounds__(1024) void topk_kernel(const float* __restrict__ score,
                                                    float* __restrict__ vals,
                                                    int* __restrict__ perm,
                                                    int* __restrict__ new_id) {
    __shared__ float sv[1024];
    __shared__ int si[1024];
    int g = blockIdx.x, t = threadIdx.x;
    float v = score[g * NPERG + t];
    int idx = t;
    for (int k = 2; k <= 1024; k <<= 1) {
        for (int j = k >> 1; j > 0; j >>= 1) {
            bool desc = ((t & k) == 0);
            bool up = (t & j) != 0;
            float vb; int ib;
            if (j >= 64) {
                sv[t] = v; si[t] = idx;
                __syncthreads();
                vb = sv[t ^ j]; ib = si[t ^ j];
                bool cmp = (v > vb) || (v == vb && idx < ib);  // lax.top_k tie rule
                bool keep = up ? (cmp != desc) : (cmp == desc);
                if (!keep) { v = vb; idx = ib; }
                __syncthreads();
            } else {
                vb = __shfl_xor(v, j);
                ib = __shfl_xor(idx, j);
                bool cmp = (v > vb) || (v == vb && idx < ib);
                bool keep = up ? (cmp != desc) : (cmp == desc);
                if (!keep) { v = vb; idx = ib; }
            }
        }
    }
    if (t < KEEP) {
        int node = g * NPERG + idx;
        int slot = g * KEEP + t;
        vals[slot] = v;
        perm[slot] = node;
        new_id[node] = slot;
    }
}

// ---------------- FUSED: deg2/dinv2 via CSR walk (blocks 0..63) --------------
// ---------------- + GEMM2 (vals*h[perm]) @ W2 MFMA, bf16-packed out ----------
__global__ __launch_bounds__(512) void g2deg_kernel(
    const unsigned short* __restrict__ csr16, const int* __restrict__ node_base,
    const int* __restrict__ deg,
    const int* __restrict__ new_id, float* __restrict__ dinv2,
    const unsigned int* __restrict__ hb, const int* __restrict__ perm,
    const float* __restrict__ vals, const unsigned short* __restrict__ Wtb,
    unsigned int* __restrict__ Cb) {
    int bid = blockIdx.x, t = threadIdx.x;
    if (bid < NGRAPH) {
        int g = bid;
        int kb = g * KEEP;
        int gb = g * NPERG;
        int node = perm[kb + t];            // 512 threads, one kept node each
        int base = node_base[node], cnt = deg[node];
        int c = 0;
        int j = 0;
        for (; j + 3 < cnt; j += 4) {
            int n0 = new_id[gb + csr16[base + j]];
            int n1 = new_id[gb + csr16[base + j + 1]];
            int n2 = new_id[gb + csr16[base + j + 2]];
            int n3 = new_id[gb + csr16[base + j + 3]];
            c += (n0 >= 0) + (n1 >= 0) + (n2 >= 0) + (n3 >= 0);
        }
        for (; j < cnt; j++) c += (new_id[gb + csr16[base + j]] >= 0) ? 1 : 0;
        dinv2[kb + t] = rsqrtf((float)c + 1.0f);
        return;
    }
    // ---- GEMM2 path: 8 waves/block, 16 rows/wave = 128 rows/block ----
    int row0 = (bid - NGRAPH) * 128;
    int wave = t >> 6, lane = t & 63;
    int r0 = row0 + wave * 16;
    int m = r0 + (lane & 15);
    int ko = (lane >> 4) * 8;
    float sc = vals[m];
    const unsigned int* arow = hb + (size_t)perm[m] * 64 + (ko >> 1);
    bf16x8 afr[4];
#pragma unroll
    for (int kk = 0; kk < 4; kk++) {
        uint4 q = *(const uint4*)(arow + kk * 16);
        bf16x8 a;
        a[0] = (short)f2bf(bf2f((unsigned short)q.x) * sc);
        a[1] = (short)f2bf(bf2f((unsigned short)(q.x >> 16)) * sc);
        a[2] = (short)f2bf(bf2f((unsigned short)q.y) * sc);
        a[3] = (short)f2bf(bf2f((unsigned short)(q.y >> 16)) * sc);
        a[4] = (short)f2bf(bf2f((unsigned short)q.z) * sc);
        a[5] = (short)f2bf(bf2f((unsigned short)(q.z >> 16)) * sc);
        a[6] = (short)f2bf(bf2f((unsigned short)q.w) * sc);
        a[7] = (short)f2bf(bf2f((unsigned short)(q.w >> 16)) * sc);
        afr[kk] = a;
    }
    f32x4 acc[8];
#pragma unroll
    for (int c = 0; c < 8; c++) acc[c] = (f32x4){0.f, 0.f, 0.f, 0.f};
    const unsigned short* brow = Wtb + (lane & 15) * HD + ko;
#pragma unroll
    for (int kk = 0; kk < 4; kk++) {
#pragma unroll
        for (int c = 0; c < 8; c++) {
            bf16x8 b = *(const bf16x8*)(brow + c * 16 * HD + kk * 32);
            acc[c] = __builtin_amdgcn_mfma_f32_16x16x32_bf16(afr[kk], b, acc[c], 0, 0, 0);
        }
    }
    int orow0 = r0 + (lane >> 4) * 4;
    bool even = !(lane & 1);
#pragma unroll
    for (int c = 0; c < 8; c++) {
#pragma unroll
        for (int j = 0; j < 4; j++) {
            float v = acc[c][j];
            float pt = __shfl_xor(v, 1);
            if (even) {
                unsigned int u = (unsigned int)f2bf(v) | ((unsigned int)f2bf(pt) << 16);
                Cb[(size_t)(orow0 + j) * 64 + ((c * 16 + (lane & 15)) >> 1)] = u;
            }
        }
    }
}

// ---------------- conv2 aggregate: 16 nodes/block, reg-accum + pool ----------
// 2048 blocks; each wave handles 4 sequential kept nodes, accumulating relu
// outputs in REGISTERS. One LDS combine per wave + one global atomic flush
// per block: pooled global atomics 1M -> 262K (contention 128 -> 32-way).
__global__ __launch_bounds__(256) void s2_pull(const unsigned short* __restrict__ csr16,
                                               const int* __restrict__ node_base,
                                               const int* __restrict__ deg,
                                               const int* __restrict__ perm,
                                               const int* __restrict__ new_id,
                                               const float* __restrict__ dinv2,
                                               const unsigned int* __restrict__ xwb2,
                                               const float* __restrict__ b2,
                                               float* __restrict__ pooled) {
    __shared__ float pr[HD];
    __shared__ int cnk[4][64];
    __shared__ float cds[4][64];
    int tid = threadIdx.x;
    if (tid < HD) pr[tid] = 0.f;
    __syncthreads();
    int b = blockIdx.x;              // 2048 blocks = 64 graphs x 32
    int xcd = b & 7, j = b >> 3;
    int g = (j >> 5) * 8 + xcd;
    int q = j & 31;
    int wv = tid >> 6;
    int lane = tid & 63;
    float2 bb = ((const float2*)b2)[lane];
    float po0 = 0.f, po1 = 0.f;
#pragma unroll
    for (int it = 0; it < 4; it++) {
        int m = g * KEEP + q * 16 + wv * 4 + it;
        int node = perm[m];
        int gb = node & ~(NPERG - 1);
        int base = node_base[node], cnt = deg[node];
        int nk = 0; float ds = 0.f;
        if (lane < cnt) {
            int ns = new_id[gb + csr16[base + lane]];
            if (ns >= 0) { nk = ns; ds = dinv2[ns]; }
        }
        unsigned long long msk = __ballot(ds != 0.f);
        int pos = __popcll(msk & ((1ull << lane) - 1ull));
        if (ds != 0.f) { cnk[wv][pos] = nk; cds[wv][pos] = ds; }
        int na = __popcll(msk);
        float a0 = 0.f, a1 = 0.f;
        int k = 0;
        for (; k + 7 < na; k += 8) {
            int s0 = cnk[wv][k],     s1 = cnk[wv][k + 1];
            int s2 = cnk[wv][k + 2], s3 = cnk[wv][k + 3];
            int s4 = cnk[wv][k + 4], s5 = cnk[wv][k + 5];
            int s6 = cnk[wv][k + 6], s7 = cnk[wv][k + 7];
            float d0 = cds[wv][k],     d1 = cds[wv][k + 1];
            float d2 = cds[wv][k + 2], d3 = cds[wv][k + 3];
            float d4 = cds[wv][k + 4], d5 = cds[wv][k + 5];
            float d6 = cds[wv][k + 6], d7 = cds[wv][k + 7];
            unsigned int u0 = xwb2[(size_t)s0 * 64 + lane];
            unsigned int u1 = xwb2[(size_t)s1 * 64 + lane];
            unsigned int u2 = xwb2[(size_t)s2 * 64 + lane];
            unsigned int u3 = xwb2[(size_t)s3 * 64 + lane];
            unsigned int u4 = xwb2[(size_t)s4 * 64 + lane];
            unsigned int u5 = xwb2[(size_t)s5 * 64 + lane];
            unsigned int u6 = xwb2[(size_t)s6 * 64 + lane];
            unsigned int u7 = xwb2[(size_t)s7 * 64 + lane];
            a0 += d0 * __uint_as_float(u0 << 16); a1 += d0 * __uint_as_float(u0 & 0xFFFF0000u);
            a0 += d1 * __uint_as_float(u1 << 16); a1 += d1 * __uint_as_float(u1 & 0xFFFF0000u);
            a0 += d2 * __uint_as_float(u2 << 16); a1 += d2 * __uint_as_float(u2 & 0xFFFF0000u);
            a0 += d3 * __uint_as_float(u3 << 16); a1 += d3 * __uint_as_float(u3 & 0xFFFF0000u);
            a0 += d4 * __uint_as_float(u4 << 16); a1 += d4 * __uint_as_float(u4 & 0xFFFF0000u);
            a0 += d5 * __uint_as_float(u5 << 16); a1 += d5 * __uint_as_float(u5 & 0xFFFF0000u);
            a0 += d6 * __uint_as_float(u6 << 16); a1 += d6 * __uint_as_float(u6 & 0xFFFF0000u);
            a0 += d7 * __uint_as_float(u7 << 16); a1 += d7 * __uint_as_float(u7 & 0xFFFF0000u);
        }
        for (; k + 3 < na; k += 4) {
            int s0 = cnk[wv][k], s1 = cnk[wv][k + 1];
            int s2 = cnk[wv][k + 2], s3 = cnk[wv][k + 3];
            float d0 = cds[wv][k], d1 = cds[wv][k + 1];
            float d2 = cds[wv][k + 2], d3 = cds[wv][k + 3];
            unsigned int u0 = xwb2[(size_t)s0 * 64 + lane];
            unsigned int u1 = xwb2[(size_t)s1 * 64 + lane];
            unsigned int u2 = xwb2[(size_t)s2 * 64 + lane];
            unsigned int u3 = xwb2[(size_t)s3 * 64 + lane];
            a0 += d0 * __uint_as_float(u0 << 16); a1 += d0 * __uint_as_float(u0 & 0xFFFF0000u);
            a0 += d1 * __uint_as_float(u1 << 16); a1 += d1 * __uint_as_float(u1 & 0xFFFF0000u);
            a0 += d2 * __uint_as_float(u2 << 16); a1 += d2 * __uint_as_float(u2 & 0xFFFF0000u);
            a0 += d3 * __uint_as_float(u3 << 16); a1 += d3 * __uint_as_float(u3 & 0xFFFF0000u);
        }
        for (; k < na; k++) {
            int sk = cnk[wv][k];
            float dk = cds[wv][k];
            unsigned int u = xwb2[(size_t)sk * 64 + lane];
            a0 += dk * __uint_as_float(u << 16); a1 += dk * __uint_as_float(u & 0xFFFF0000u);
        }
        for (int kk = 64; kk < cnt; kk++) {    // deg>64 cold path
            int ns = new_id[gb + csr16[base + kk]];
            if (ns >= 0) {
                float dk = dinv2[ns];
                unsigned int u = xwb2[(size_t)ns * 64 + lane];
                a0 += dk * __uint_as_float(u << 16); a1 += dk * __uint_as_float(u & 0xFFFF0000u);
            }
        }
        float dn = dinv2[m];
        float self = dn * dn;
        unsigned int us = xwb2[(size_t)m * 64 + lane];
        po0 += fmaxf(dn * a0 + self * __uint_as_float(us << 16) + bb.x, 0.f);
        po1 += fmaxf(dn * a1 + self * __uint_as_float(us & 0xFFFF0000u) + bb.y, 0.f);
    }
    atomicAdd(&pr[lane * 2], po0);
    atomicAdd(&pr[lane * 2 + 1], po1);
    __syncthreads();
    if (tid < HD) atomicAdd(&pooled[g * HD + tid], pr[tid]);
}

// ---------------- final linear: out = (pooled/512) @ Wl + bl -----------------
__global__ __launch_bounds__(128) void outk_kernel(const float* __restrict__ pooled,
                                                   const float* __restrict__ Wl,
                                                   const float* __restrict__ bl,
                                                   void* __restrict__ outv,
                                                   const int* __restrict__ flag) {
    int g = blockIdx.x, t = threadIdx.x;  // 128
    __shared__ float sp[HD];
    sp[t] = pooled[g * HD + t] * (1.0f / KEEP);
    __syncthreads();
    if (t < NC) {
        float acc = bl[t];
        for (int hh = 0; hh < HD; hh++) acc += sp[hh] * Wl[hh * NC + t];
        if (flag[0]) ((unsigned short*)outv)[g * NC + t] = f2bf(acc);
        else         ((float*)outv)[g * NC + t] = acc;
    }
}

extern "C" void kernel_launch(void* const* d_in, const int* in_sizes, int n_in,
                              void* d_out, int out_size, void* d_ws, size_t ws_size,
                              hipStream_t stream) {
    const int* ei   = (const int*)d_in[1];
    const int* srcv = ei;
    const int* dstv = ei + NEDGES;

    char* w = (char*)d_ws;
    const size_t MB = 1u << 20;
    const size_t KB = 1024;
    float* dinv1     = (float*)(w + 0);                 // 256 KB
    float* score     = (float*)(w + 256 * KB);          // 256 KB
    float* vals      = (float*)(w + 512 * KB);          // 128 KB
    int*   perm      = (int*)(w + 640 * KB);            // 128 KB
    int*   new_id    = (int*)(w + 768 * KB);            // 256 KB
    int*   deg1      = (int*)(w + 1024 * KB);           // 256 KB
    int*   node_base = (int*)(w + 1280 * KB);           // 256 KB
    float* dinv2     = (float*)(w + 1536 * KB);         // 128 KB
    float* invnorm   = (float*)(w + 1664 * KB);
    int*   flag      = (int*)(w + 1664 * KB + 64);
    int*   ghist     = (int*)(w + 1664 * KB + 1024);
    int*   gcur0     = (int*)(w + 1664 * KB + 2048);
    float* cw        = (float*)(w + 1700 * KB);         // 135 KB canonical weights
    float* pooled    = (float*)(w + 1840 * KB);         // 32 KB
    unsigned short* w1t = (unsigned short*)(w + 1880 * KB);  // 32 KB bf16 W1^T
    unsigned short* w2t = (unsigned short*)(w + 1912 * KB);  // 32 KB bf16 W2^T
    unsigned int* xw1b = (unsigned int*)(w + 2 * MB);   // [2,18) MB  bf16-packed xw1
    unsigned int* xw2b = (unsigned int*)(w + 18 * MB);  // [18,26) MB bf16-packed xw2
    unsigned int* hb = (unsigned int*)(w + 34 * MB);    // [34,50) MB bf16-packed h
    unsigned int* elist    = (unsigned int*)(w + 66 * MB);   // [66,71.25) MB fixed-stride
    unsigned short* csr16  = (unsigned short*)(w + 72 * MB); // [72,74.63) MB

    float* W1f = cw + OW1; float* W2f = cw + OW2; float* Wlf = cw + OWL;
    float* b1f = cw + OB1; float* b2f = cw + OB2; float* pf  = cw + OP;
    float* blf = cw + OBL;
    (void)W1f; (void)W2f;

    // zero ghist + gcur0 (binning in prep needs them zeroed; same-kernel init
    // would race). Covers [ghist, gcur0+64) = 1280 B.
    hipMemsetAsync(w + 1664 * KB + 1024, 0, 1280 + 256, stream);

    prep_kernel<<<648, 256, 0, stream>>>(d_in[3], d_in[4], d_in[5], d_in[6], d_in[7],
                                         d_in[8], d_in[9], flag, cw, invnorm, new_id,
                                         ghist, gcur0, pooled, w1t, w2t, srcv, dstv,
                                         elist);
    g1csr_kernel<<<NGRAPH + NNODES / 256, 1024, 0, stream>>>(
        elist, ghist, csr16, node_base, deg1, dinv1, d_in[0], w1t, xw1b, flag);
    s1_pull<<<NNODES / 4, 256, 0, stream>>>(csr16, node_base, deg1, dinv1, xw1b, b1f, pf,
                                            invnorm, hb, score);
    topk_kernel<<<NGRAPH, 1024, 0, stream>>>(score, vals, perm, new_id);
    g2deg_kernel<<<NGRAPH + M2 / 128, 512, 0, stream>>>(
        csr16, node_base, deg1, new_id, dinv2, hb, perm, vals, w2t, xw2b);
    s2_pull<<<2048, 256, 0, stream>>>(csr16, node_base, deg1, perm, new_id, dinv2,
                                      xw2b, b2f, pooled);
    outk_kernel<<<NGRAPH, 128, 0, stream>>>(pooled, Wlf, blf, d_out, flag);

    (void)in_sizes; (void)n_in; (void)out_size; (void)ws_size;
}